// Round 1
// baseline (2463.597 us; speedup 1.0000x reference)
//
#include <hip/hip_runtime.h>
#include <math.h>

// Problem constants
#define T_TOK   4096            // B*S
#define D_MODEL 768
#define H_HEADS 12
#define HDIM    64
#define S_SEQ   512
#define B_BATCH 8
#define E_EXP   8
#define FF_DIM  3072
#define GBK     16              // GEMM K-tile

__device__ __forceinline__ float gelu_exact(float x) {
    return 0.5f * x * (1.0f + erff(x * 0.7071067811865476f));
}

// ---------------- LayerNorm: one block per token row ----------------
__global__ void __launch_bounds__(256) ln_kernel(const float* __restrict__ x,
                                                 const float* __restrict__ g,
                                                 const float* __restrict__ b,
                                                 float* __restrict__ out) {
    int row = blockIdx.x;
    const float* xr = x + (size_t)row * D_MODEL;
    int tid = threadIdx.x;
    float v0 = xr[tid];
    float v1 = xr[tid + 256];
    float v2 = xr[tid + 512];
    float s = v0 + v1 + v2;
    float q = v0 * v0 + v1 * v1 + v2 * v2;
    for (int off = 32; off; off >>= 1) {
        s += __shfl_down(s, off);
        q += __shfl_down(q, off);
    }
    __shared__ float rs[4], rq[4], stats[2];
    int wid = tid >> 6, lane = tid & 63;
    if (lane == 0) { rs[wid] = s; rq[wid] = q; }
    __syncthreads();
    if (tid == 0) {
        float ts = rs[0] + rs[1] + rs[2] + rs[3];
        float tq = rq[0] + rq[1] + rq[2] + rq[3];
        float mu = ts * (1.0f / 768.0f);
        float var = tq * (1.0f / 768.0f) - mu * mu;
        stats[0] = mu;
        stats[1] = rsqrtf(var + 1e-5f);
    }
    __syncthreads();
    float mu = stats[0], rstd = stats[1];
    float* orow = out + (size_t)row * D_MODEL;
    orow[tid]       = (v0 - mu) * rstd * g[tid]       + b[tid];
    orow[tid + 256] = (v1 - mu) * rstd * g[tid + 256] + b[tid + 256];
    orow[tid + 512] = (v2 - mu) * rstd * g[tid + 512] + b[tid + 512];
}

// ---------------- Attention: one wave per (b, h, q-row) ----------------
// qkv row layout per token: [q(H*64) | k(H*64) | v(H*64)], row stride 3*D.
__global__ void __launch_bounds__(64) attn_kernel(const float* __restrict__ qkv,
                                                  float* __restrict__ o) {
    int qi = blockIdx.x, h = blockIdx.y, b = blockIdx.z;
    int lane = threadIdx.x;
    __shared__ float qs[64];
    __shared__ float p[512];
    const size_t rstride = 3 * D_MODEL;
    const float* qrow = qkv + (size_t)(b * S_SEQ + qi) * rstride + h * HDIM;
    qs[lane] = qrow[lane] * 0.125f;   // scale = HD^-0.5 = 1/8
    __syncthreads();
    const float* kbase = qkv + (size_t)b * S_SEQ * rstride + D_MODEL + h * HDIM;
    float sc[8];
#pragma unroll
    for (int i = 0; i < 8; i++) {
        int j = lane + 64 * i;
        const float* kp = kbase + (size_t)j * rstride;
        float s = 0.f;
#pragma unroll
        for (int d = 0; d < 64; d++) s += qs[d] * kp[d];
        sc[i] = s;
    }
    float m = sc[0];
#pragma unroll
    for (int i = 1; i < 8; i++) m = fmaxf(m, sc[i]);
    for (int off = 32; off; off >>= 1) m = fmaxf(m, __shfl_xor(m, off));
    float l = 0.f;
#pragma unroll
    for (int i = 0; i < 8; i++) {
        float e = __expf(sc[i] - m);
        p[lane + 64 * i] = e;
        l += e;
    }
    for (int off = 32; off; off >>= 1) l += __shfl_xor(l, off);
    __syncthreads();
    const float* vbase = qkv + (size_t)b * S_SEQ * rstride + 2 * D_MODEL + h * HDIM;
    float acc = 0.f;
#pragma unroll 8
    for (int j = 0; j < 512; j++) acc += p[j] * vbase[(size_t)j * rstride + lane];
    o[(size_t)(b * S_SEQ + qi) * D_MODEL + h * HDIM + lane] = acc / l;
}

// ---------------- Router: logits + argmax + histogram ----------------
__global__ void __launch_bounds__(64) router_kernel(const float* __restrict__ h2,
                                                    const float* __restrict__ sw,
                                                    const float* __restrict__ sb,
                                                    int* __restrict__ routes,
                                                    int* __restrict__ counts) {
    int t = blockIdx.x;
    int lane = threadIdx.x;
    const float* hr = h2 + (size_t)t * D_MODEL;
    float acc[8] = {};
    for (int d = lane; d < D_MODEL; d += 64) {
        float hv = hr[d];
        const float* wr = sw + (size_t)d * 8;
#pragma unroll
        for (int e = 0; e < 8; e++) acc[e] += hv * wr[e];
    }
#pragma unroll
    for (int e = 0; e < 8; e++)
        for (int off = 32; off; off >>= 1) acc[e] += __shfl_down(acc[e], off);
    if (lane == 0) {
        int best = 0;
        float bv = acc[0] + sb[0];
#pragma unroll
        for (int e = 1; e < 8; e++) {
            float v = acc[e] + sb[e];
            if (v > bv) { bv = v; best = e; }   // strict > == first-max (jnp.argmax)
        }
        routes[t] = best;
        atomicAdd(&counts[best], 1);
    }
}

__global__ void zero_counts(int* counts, int* cursor) {
    if (threadIdx.x < 8) { counts[threadIdx.x] = 0; cursor[threadIdx.x] = 0; }
}

// Build padded per-expert tile plan (serial, trivial size: 8 experts, <=72 tiles)
__global__ void moe_plan(const int* __restrict__ counts, int* pad_base, int* tile_e,
                         int* tile_row0, int* tile_valid, int* ntiles) {
    if (threadIdx.x == 0 && blockIdx.x == 0) {
        int base = 0, nt = 0;
        for (int e = 0; e < E_EXP; e++) {
            pad_base[e] = base;
            int c = counts[e];
            int nte = (c + 63) >> 6;
            for (int j = 0; j < nte; j++) {
                tile_e[nt] = e;
                tile_row0[nt] = base + j * 64;
                int v = c - j * 64;
                tile_valid[nt] = v > 64 ? 64 : v;
                nt++;
            }
            base += nte * 64;
        }
        ntiles[0] = nt;
    }
}

__global__ void __launch_bounds__(256) scatter_kernel(const int* __restrict__ routes,
                                                      const int* __restrict__ pad_base,
                                                      int* __restrict__ cursor,
                                                      int* __restrict__ perm) {
    int t = blockIdx.x * 256 + threadIdx.x;
    if (t < T_TOK) {
        int e = routes[t];
        int pos = atomicAdd(&cursor[e], 1);
        perm[pad_base[e] + pos] = t;
    }
}

// ---------------- Tiled fp32 GEMM, 64x64 tile, 256 threads, 4x4/thread ----
// MODE 0: C = A@B                               (QKV)
// MODE 1: C = resid + A@B + bias                (proj + residual)
// MODE 2: grouped rows gathered via perm; C[grouped] = gelu(A_g@B_e + bias_e)  (MoE up)
// MODE 3: grouped A; out[perm[g]] = resid[perm[g]] + gelu(A@B_e + bias_e)      (MoE down)
template <int MODE>
__global__ void __launch_bounds__(256) gemm64(const float* __restrict__ A,
                                              const float* __restrict__ Bw,
                                              const float* __restrict__ bias,
                                              const float* __restrict__ resid,
                                              float* __restrict__ C, int N, int K,
                                              const int* __restrict__ perm,
                                              const int* __restrict__ tile_e,
                                              const int* __restrict__ tile_row0,
                                              const int* __restrict__ tile_valid,
                                              const int* __restrict__ ntiles) {
    __shared__ float As[GBK][68];   // transposed A tile, padded (writes stride 68)
    __shared__ float Bs[GBK][64];
    __shared__ int rowmap[64];

    int e = 0, row0 = 0, valid = 64;
    if constexpr (MODE >= 2) {
        if (blockIdx.y >= (unsigned)ntiles[0]) return;
        e = tile_e[blockIdx.y];
        row0 = tile_row0[blockIdx.y];
        valid = tile_valid[blockIdx.y];
        Bw += (size_t)e * K * N;
        bias += (size_t)e * N;
        if constexpr (MODE == 2) {
            if (threadIdx.x < 64) {
                int m = threadIdx.x;
                rowmap[m] = (m < valid) ? perm[row0 + m] : -1;
            }
            __syncthreads();
        }
    }

    int tid = threadIdx.x;
    int tx = tid & 15, ty = tid >> 4;
    int n0 = blockIdx.x * 64;
    int m_stage = tid >> 2;          // 0..63
    int k_stage = (tid & 3) * 4;     // 0,4,8,12

    const float* Arow;
    if constexpr (MODE == 2) {
        int gidx = rowmap[m_stage];
        Arow = (gidx >= 0) ? (A + (size_t)gidx * K) : nullptr;
    } else if constexpr (MODE == 3) {
        Arow = (m_stage < valid) ? (A + (size_t)(row0 + m_stage) * K) : nullptr;
    } else {
        Arow = A + (size_t)(blockIdx.y * 64 + m_stage) * K;
    }

    float c[4][4] = {};
    for (int k0 = 0; k0 < K; k0 += GBK) {
        float4 av = make_float4(0.f, 0.f, 0.f, 0.f);
        if (Arow) av = *(const float4*)(Arow + k0 + k_stage);
        As[k_stage + 0][m_stage] = av.x;
        As[k_stage + 1][m_stage] = av.y;
        As[k_stage + 2][m_stage] = av.z;
        As[k_stage + 3][m_stage] = av.w;
        int kb = tid >> 4;           // 0..15
        int nb = (tid & 15) * 4;
        *(float4*)&Bs[kb][nb] = *(const float4*)(Bw + (size_t)(k0 + kb) * N + n0 + nb);
        __syncthreads();
#pragma unroll
        for (int k = 0; k < GBK; k++) {
            float4 a = *(const float4*)&As[k][ty * 4];
            float4 b = *(const float4*)&Bs[k][tx * 4];
            c[0][0] += a.x * b.x; c[0][1] += a.x * b.y; c[0][2] += a.x * b.z; c[0][3] += a.x * b.w;
            c[1][0] += a.y * b.x; c[1][1] += a.y * b.y; c[1][2] += a.y * b.z; c[1][3] += a.y * b.w;
            c[2][0] += a.z * b.x; c[2][1] += a.z * b.y; c[2][2] += a.z * b.z; c[2][3] += a.z * b.w;
            c[3][0] += a.w * b.x; c[3][1] += a.w * b.y; c[3][2] += a.w * b.z; c[3][3] += a.w * b.w;
        }
        __syncthreads();
    }

#pragma unroll
    for (int i = 0; i < 4; i++) {
        int mloc = ty * 4 + i;
        int n = n0 + tx * 4;
        if constexpr (MODE == 0) {
            size_t idx = (size_t)(blockIdx.y * 64 + mloc) * N + n;
            C[idx + 0] = c[i][0]; C[idx + 1] = c[i][1];
            C[idx + 2] = c[i][2]; C[idx + 3] = c[i][3];
        } else if constexpr (MODE == 1) {
            size_t idx = (size_t)(blockIdx.y * 64 + mloc) * N + n;
#pragma unroll
            for (int j = 0; j < 4; j++) C[idx + j] = resid[idx + j] + c[i][j] + bias[n + j];
        } else if constexpr (MODE == 2) {
            if (mloc < valid) {
                size_t idx = (size_t)(row0 + mloc) * N + n;
#pragma unroll
                for (int j = 0; j < 4; j++) C[idx + j] = gelu_exact(c[i][j] + bias[n + j]);
            }
        } else {  // MODE 3
            if (mloc < valid) {
                int t = perm[row0 + mloc];
                size_t idx = (size_t)t * N + n;
#pragma unroll
                for (int j = 0; j < 4; j++)
                    C[idx + j] = resid[idx + j] + gelu_exact(c[i][j] + bias[n + j]);
            }
        }
    }
}

extern "C" void kernel_launch(void* const* d_in, const int* in_sizes, int n_in,
                              void* d_out, int out_size, void* d_ws, size_t ws_size,
                              hipStream_t stream) {
    const float* x      = (const float*)d_in[0];
    // d_in[1] = indexes_list (unused, as in reference)
    const float* ln1_g  = (const float*)d_in[2];
    const float* ln1_b  = (const float*)d_in[3];
    const float* qkv_w  = (const float*)d_in[4];
    const float* proj_w = (const float*)d_in[5];
    const float* proj_b = (const float*)d_in[6];
    const float* ln2_g  = (const float*)d_in[7];
    const float* ln2_b  = (const float*)d_in[8];
    const float* sw     = (const float*)d_in[9];
    const float* sb     = (const float*)d_in[10];
    const float* w1     = (const float*)d_in[11];
    const float* b1     = (const float*)d_in[12];
    const float* w2     = (const float*)d_in[13];
    const float* b2     = (const float*)d_in[14];
    float* out = (float*)d_out;

    // Workspace layout (floats). qkv and y1 share the "big" region: qkv is dead
    // after the attention kernel; y1 is written two kernels later (stream-serial).
    // d_out doubles as attention-output scratch (fully overwritten by MoE GEMM2).
    float* ws  = (float*)d_ws;
    float* h   = ws;                                   // T*D   (ln1 out; later ln2 out)
    float* x1  = h + (size_t)T_TOK * D_MODEL;          // T*D   (post-attention residual)
    float* big = x1 + (size_t)T_TOK * D_MODEL;
    float* qkv = big;                                  // T*3D
    float* y1  = big;                                  // (T + E*64)*FF grouped
    float* o   = out;                                  // attention out scratch
    int* ip        = (int*)(big + (size_t)(T_TOK + E_EXP * 64) * FF_DIM);
    int* routes    = ip;                    // 4096
    int* perm      = routes + T_TOK;        // 4608
    int* counts    = perm + T_TOK + E_EXP * 64;
    int* cursor    = counts + 8;
    int* pad_base  = cursor + 8;
    int* tile_e    = pad_base + 8;
    int* tile_row0 = tile_e + 80;
    int* tile_valid= tile_row0 + 80;
    int* ntiles    = tile_valid + 80;

    // 1. LN1: x -> h
    ln_kernel<<<T_TOK, 256, 0, stream>>>(x, ln1_g, ln1_b, h);
    // 2. QKV: h @ qkv_w -> qkv   [4096 x 2304, K=768]
    gemm64<0><<<dim3(2304 / 64, T_TOK / 64), 256, 0, stream>>>(
        h, qkv_w, nullptr, nullptr, qkv, 2304, 768,
        nullptr, nullptr, nullptr, nullptr, nullptr);
    // 3. Attention: qkv -> o (d_out scratch)
    attn_kernel<<<dim3(S_SEQ, H_HEADS, B_BATCH), 64, 0, stream>>>(qkv, o);
    // 4. Proj + residual: x1 = x + o @ proj_w + proj_b   [4096 x 768, K=768]
    gemm64<1><<<dim3(768 / 64, T_TOK / 64), 256, 0, stream>>>(
        o, proj_w, proj_b, x, x1, 768, 768,
        nullptr, nullptr, nullptr, nullptr, nullptr);
    // 5. LN2: x1 -> h (reused)
    ln_kernel<<<T_TOK, 256, 0, stream>>>(x1, ln2_g, ln2_b, h);
    // 6-9. Routing: logits/argmax/histogram -> tile plan -> scatter perm
    zero_counts<<<1, 64, 0, stream>>>(counts, cursor);
    router_kernel<<<T_TOK, 64, 0, stream>>>(h, sw, sb, routes, counts);
    moe_plan<<<1, 1, 0, stream>>>(counts, pad_base, tile_e, tile_row0, tile_valid, ntiles);
    scatter_kernel<<<T_TOK / 256, 256, 0, stream>>>(routes, pad_base, cursor, perm);
    // 10. MoE up: y1[grouped] = gelu(h2[perm] @ w1[e] + b1[e])   [N=3072, K=768]
    gemm64<2><<<dim3(FF_DIM / 64, 72), 256, 0, stream>>>(
        h, w1, b1, nullptr, y1, FF_DIM, D_MODEL,
        perm, tile_e, tile_row0, tile_valid, ntiles);
    // 11. MoE down + residual scatter: out[t] = x1[t] + gelu(y1 @ w2[e] + b2[e])  [N=768, K=3072]
    gemm64<3><<<dim3(D_MODEL / 64, 72), 256, 0, stream>>>(
        y1, w2, b2, x1, out, D_MODEL, FF_DIM,
        perm, tile_e, tile_row0, tile_valid, ntiles);
}

// Round 2
// 1280.701 us; speedup vs baseline: 1.9236x; 1.9236x over previous
//
#include <hip/hip_runtime.h>
#include <math.h>

// Problem constants
#define T_TOK   4096            // B*S
#define D_MODEL 768
#define H_HEADS 12
#define HDIM    64
#define S_SEQ   512
#define B_BATCH 8
#define E_EXP   8
#define FF_DIM  3072
#define GBK     16              // GEMM K-tile

__device__ __forceinline__ float gelu_exact(float x) {
    return 0.5f * x * (1.0f + erff(x * 0.7071067811865476f));
}

// ---------------- LayerNorm: one block per token row ----------------
__global__ void __launch_bounds__(256) ln_kernel(const float* __restrict__ x,
                                                 const float* __restrict__ g,
                                                 const float* __restrict__ b,
                                                 float* __restrict__ out) {
    int row = blockIdx.x;
    const float* xr = x + (size_t)row * D_MODEL;
    int tid = threadIdx.x;
    float v0 = xr[tid];
    float v1 = xr[tid + 256];
    float v2 = xr[tid + 512];
    float s = v0 + v1 + v2;
    float q = v0 * v0 + v1 * v1 + v2 * v2;
    for (int off = 32; off; off >>= 1) {
        s += __shfl_down(s, off);
        q += __shfl_down(q, off);
    }
    __shared__ float rs[4], rq[4], stats[2];
    int wid = tid >> 6, lane = tid & 63;
    if (lane == 0) { rs[wid] = s; rq[wid] = q; }
    __syncthreads();
    if (tid == 0) {
        float ts = rs[0] + rs[1] + rs[2] + rs[3];
        float tq = rq[0] + rq[1] + rq[2] + rq[3];
        float mu = ts * (1.0f / 768.0f);
        float var = tq * (1.0f / 768.0f) - mu * mu;
        stats[0] = mu;
        stats[1] = rsqrtf(var + 1e-5f);
    }
    __syncthreads();
    float mu = stats[0], rstd = stats[1];
    float* orow = out + (size_t)row * D_MODEL;
    orow[tid]       = (v0 - mu) * rstd * g[tid]       + b[tid];
    orow[tid + 256] = (v1 - mu) * rstd * g[tid + 256] + b[tid + 256];
    orow[tid + 512] = (v2 - mu) * rstd * g[tid + 512] + b[tid + 512];
}

// ---------------- Tiled flash attention ----------------
// One block per (q-tile of 64 rows, head, batch). 256 threads, 4x4 micro-tile.
// LDS: Qst/Kst transposed [dim][row] (pad 68 keeps float4 reads 16B-aligned);
// Kst is reused as the P-transposed buffer after S-compute (saves 17 KB ->
// 51 KB total -> 3 blocks/CU -> all 768 blocks co-resident).
__global__ void __launch_bounds__(256) attn_tile(const float* __restrict__ qkv,
                                                 float* __restrict__ o) {
    __shared__ float Qst[64][68];   // [d][r], pre-scaled by 1/8
    __shared__ float Kst[64][68];   // [d][c]; later aliased as Pst[key][row]
    __shared__ float Vs [64][68];   // [key][d]
    int qt = blockIdx.x, hh = blockIdx.y, bb = blockIdx.z;
    int tid = threadIdx.x;
    int tx = tid & 15, ty = tid >> 4;
    const size_t rstride = 3 * D_MODEL;
    const float* base = qkv + (size_t)bb * S_SEQ * rstride + hh * HDIM;

    // Stage Q transposed & scaled (rows qt*64..qt*64+63)
    {
        int f4 = tid & 15;          // which float4 of the 64-dim row
        int r0 = tid >> 4;
        for (int rr = 0; rr < 64; rr += 16) {
            int r = r0 + rr;
            const float* qrow = base + (size_t)(qt * 64 + r) * rstride;
            float4 v = *(const float4*)(qrow + f4 * 4);
            Qst[f4 * 4 + 0][r] = v.x * 0.125f;
            Qst[f4 * 4 + 1][r] = v.y * 0.125f;
            Qst[f4 * 4 + 2][r] = v.z * 0.125f;
            Qst[f4 * 4 + 3][r] = v.w * 0.125f;
        }
    }

    float m_run[4], l_run[4], o_acc[4][4];
#pragma unroll
    for (int i = 0; i < 4; i++) {
        m_run[i] = -1e30f; l_run[i] = 0.f;
#pragma unroll
        for (int j2 = 0; j2 < 4; j2++) o_acc[i][j2] = 0.f;
    }

    for (int kt = 0; kt < 8; kt++) {
        __syncthreads();   // A: prev iteration's PV reads of Kst(P)/Vs are done
        {
            int f4 = tid & 15;
            int r0 = tid >> 4;
            for (int rr = 0; rr < 64; rr += 16) {
                int r = r0 + rr;
                const float* krow = base + (size_t)(kt * 64 + r) * rstride + D_MODEL;
                float4 v = *(const float4*)(krow + f4 * 4);
                Kst[f4 * 4 + 0][r] = v.x;
                Kst[f4 * 4 + 1][r] = v.y;
                Kst[f4 * 4 + 2][r] = v.z;
                Kst[f4 * 4 + 3][r] = v.w;
                const float* vrow = base + (size_t)(kt * 64 + r) * rstride + 2 * D_MODEL;
                *(float4*)&Vs[r][f4 * 4] = *(const float4*)(vrow + f4 * 4);
            }
        }
        __syncthreads();   // B: staging visible

        // S-tile = Q @ K^T  (rows ty*4.., cols tx*4..)
        float s[4][4] = {};
#pragma unroll 8
        for (int d = 0; d < 64; d++) {
            float4 a = *(const float4*)&Qst[d][ty * 4];
            float4 b = *(const float4*)&Kst[d][tx * 4];
            s[0][0] += a.x * b.x; s[0][1] += a.x * b.y; s[0][2] += a.x * b.z; s[0][3] += a.x * b.w;
            s[1][0] += a.y * b.x; s[1][1] += a.y * b.y; s[1][2] += a.y * b.z; s[1][3] += a.y * b.w;
            s[2][0] += a.z * b.x; s[2][1] += a.z * b.y; s[2][2] += a.z * b.z; s[2][3] += a.z * b.w;
            s[3][0] += a.w * b.x; s[3][1] += a.w * b.y; s[3][2] += a.w * b.z; s[3][3] += a.w * b.w;
        }
        __syncthreads();   // C: all S reads of Kst done -> safe to overwrite as P

        // Online softmax update (row groups of 16 lanes share a row; masks<16
        // stay inside the 16-lane group, which never crosses a wave boundary)
#pragma unroll
        for (int i = 0; i < 4; i++) {
            float tm = fmaxf(fmaxf(s[i][0], s[i][1]), fmaxf(s[i][2], s[i][3]));
            tm = fmaxf(tm, __shfl_xor(tm, 1));
            tm = fmaxf(tm, __shfl_xor(tm, 2));
            tm = fmaxf(tm, __shfl_xor(tm, 4));
            tm = fmaxf(tm, __shfl_xor(tm, 8));
            float mn = fmaxf(m_run[i], tm);
            float alpha = __expf(m_run[i] - mn);
            m_run[i] = mn;
            float ts = 0.f;
#pragma unroll
            for (int j2 = 0; j2 < 4; j2++) {
                s[i][j2] = __expf(s[i][j2] - mn);
                ts += s[i][j2];
            }
            ts += __shfl_xor(ts, 1);
            ts += __shfl_xor(ts, 2);
            ts += __shfl_xor(ts, 4);
            ts += __shfl_xor(ts, 8);
            l_run[i] = l_run[i] * alpha + ts;
#pragma unroll
            for (int j2 = 0; j2 < 4; j2++) o_acc[i][j2] *= alpha;
        }

        // Write P transposed into Kst: Pst[key][row]
#pragma unroll
        for (int i = 0; i < 4; i++)
#pragma unroll
            for (int j2 = 0; j2 < 4; j2++)
                Kst[tx * 4 + j2][ty * 4 + i] = s[i][j2];
        __syncthreads();   // D: P visible

        // O += P @ V   (rows ty*4.., dims tx*4..)
#pragma unroll 8
        for (int k = 0; k < 64; k++) {
            float4 a = *(const float4*)&Kst[k][ty * 4];   // P^T[k][row]
            float4 b = *(const float4*)&Vs[k][tx * 4];
            o_acc[0][0] += a.x * b.x; o_acc[0][1] += a.x * b.y; o_acc[0][2] += a.x * b.z; o_acc[0][3] += a.x * b.w;
            o_acc[1][0] += a.y * b.x; o_acc[1][1] += a.y * b.y; o_acc[1][2] += a.y * b.z; o_acc[1][3] += a.y * b.w;
            o_acc[2][0] += a.z * b.x; o_acc[2][1] += a.z * b.y; o_acc[2][2] += a.z * b.z; o_acc[2][3] += a.z * b.w;
            o_acc[3][0] += a.w * b.x; o_acc[3][1] += a.w * b.y; o_acc[3][2] += a.w * b.z; o_acc[3][3] += a.w * b.w;
        }
    }

    float* obase = o + (size_t)(bb * S_SEQ + qt * 64) * D_MODEL + hh * HDIM;
#pragma unroll
    for (int i = 0; i < 4; i++) {
        float inv = 1.0f / l_run[i];
        float4 r;
        r.x = o_acc[i][0] * inv;
        r.y = o_acc[i][1] * inv;
        r.z = o_acc[i][2] * inv;
        r.w = o_acc[i][3] * inv;
        *(float4*)(obase + (size_t)(ty * 4 + i) * D_MODEL + tx * 4) = r;
    }
}

// ---------------- Router: logits + argmax + histogram ----------------
__global__ void __launch_bounds__(64) router_kernel(const float* __restrict__ h2,
                                                    const float* __restrict__ sw,
                                                    const float* __restrict__ sb,
                                                    int* __restrict__ routes,
                                                    int* __restrict__ counts) {
    int t = blockIdx.x;
    int lane = threadIdx.x;
    const float* hr = h2 + (size_t)t * D_MODEL;
    float acc[8] = {};
    for (int d = lane; d < D_MODEL; d += 64) {
        float hv = hr[d];
        const float* wr = sw + (size_t)d * 8;
#pragma unroll
        for (int e = 0; e < 8; e++) acc[e] += hv * wr[e];
    }
#pragma unroll
    for (int e = 0; e < 8; e++)
        for (int off = 32; off; off >>= 1) acc[e] += __shfl_down(acc[e], off);
    if (lane == 0) {
        int best = 0;
        float bv = acc[0] + sb[0];
#pragma unroll
        for (int e = 1; e < 8; e++) {
            float v = acc[e] + sb[e];
            if (v > bv) { bv = v; best = e; }   // strict > == first-max (jnp.argmax)
        }
        routes[t] = best;
        atomicAdd(&counts[best], 1);
    }
}

__global__ void zero_counts(int* counts, int* cursor) {
    if (threadIdx.x < 8) { counts[threadIdx.x] = 0; cursor[threadIdx.x] = 0; }
}

// Build padded per-expert tile plan (serial, trivial size: 8 experts, <=72 tiles)
__global__ void moe_plan(const int* __restrict__ counts, int* pad_base, int* tile_e,
                         int* tile_row0, int* tile_valid, int* ntiles) {
    if (threadIdx.x == 0 && blockIdx.x == 0) {
        int base = 0, nt = 0;
        for (int e = 0; e < E_EXP; e++) {
            pad_base[e] = base;
            int c = counts[e];
            int nte = (c + 63) >> 6;
            for (int j = 0; j < nte; j++) {
                tile_e[nt] = e;
                tile_row0[nt] = base + j * 64;
                int v = c - j * 64;
                tile_valid[nt] = v > 64 ? 64 : v;
                nt++;
            }
            base += nte * 64;
        }
        ntiles[0] = nt;
    }
}

__global__ void __launch_bounds__(256) scatter_kernel(const int* __restrict__ routes,
                                                      const int* __restrict__ pad_base,
                                                      int* __restrict__ cursor,
                                                      int* __restrict__ perm) {
    int t = blockIdx.x * 256 + threadIdx.x;
    if (t < T_TOK) {
        int e = routes[t];
        int pos = atomicAdd(&cursor[e], 1);
        perm[pad_base[e] + pos] = t;
    }
}

// ---------------- Tiled fp32 GEMM, 64x64 tile, 256 threads, 4x4/thread ----
// MODE 0: C = A@B                               (QKV)
// MODE 1: C = resid + A@B + bias                (proj + residual)
// MODE 2: grouped rows gathered via perm; C[grouped] = gelu(A_g@B_e + bias_e)  (MoE up)
// MODE 3: grouped A; out[perm[g]] = resid[perm[g]] + gelu(A@B_e + bias_e)      (MoE down)
template <int MODE>
__global__ void __launch_bounds__(256) gemm64(const float* __restrict__ A,
                                              const float* __restrict__ Bw,
                                              const float* __restrict__ bias,
                                              const float* __restrict__ resid,
                                              float* __restrict__ C, int N, int K,
                                              const int* __restrict__ perm,
                                              const int* __restrict__ tile_e,
                                              const int* __restrict__ tile_row0,
                                              const int* __restrict__ tile_valid,
                                              const int* __restrict__ ntiles) {
    __shared__ float As[GBK][68];   // transposed A tile, padded
    __shared__ float Bs[GBK][64];
    __shared__ int rowmap[64];

    int e = 0, row0 = 0, valid = 64;
    if constexpr (MODE >= 2) {
        if (blockIdx.y >= (unsigned)ntiles[0]) return;
        e = tile_e[blockIdx.y];
        row0 = tile_row0[blockIdx.y];
        valid = tile_valid[blockIdx.y];
        Bw += (size_t)e * K * N;
        bias += (size_t)e * N;
        if constexpr (MODE == 2) {
            if (threadIdx.x < 64) {
                int m = threadIdx.x;
                rowmap[m] = (m < valid) ? perm[row0 + m] : -1;
            }
            __syncthreads();
        }
    }

    int tid = threadIdx.x;
    int tx = tid & 15, ty = tid >> 4;
    int n0 = blockIdx.x * 64;
    int m_stage = tid >> 2;          // 0..63
    int k_stage = (tid & 3) * 4;     // 0,4,8,12

    const float* Arow;
    if constexpr (MODE == 2) {
        int gidx = rowmap[m_stage];
        Arow = (gidx >= 0) ? (A + (size_t)gidx * K) : nullptr;
    } else if constexpr (MODE == 3) {
        Arow = (m_stage < valid) ? (A + (size_t)(row0 + m_stage) * K) : nullptr;
    } else {
        Arow = A + (size_t)(blockIdx.y * 64 + m_stage) * K;
    }

    float c[4][4] = {};
    for (int k0 = 0; k0 < K; k0 += GBK) {
        float4 av = make_float4(0.f, 0.f, 0.f, 0.f);
        if (Arow) av = *(const float4*)(Arow + k0 + k_stage);
        As[k_stage + 0][m_stage] = av.x;
        As[k_stage + 1][m_stage] = av.y;
        As[k_stage + 2][m_stage] = av.z;
        As[k_stage + 3][m_stage] = av.w;
        int kb = tid >> 4;           // 0..15
        int nb = (tid & 15) * 4;
        *(float4*)&Bs[kb][nb] = *(const float4*)(Bw + (size_t)(k0 + kb) * N + n0 + nb);
        __syncthreads();
#pragma unroll
        for (int k = 0; k < GBK; k++) {
            float4 a = *(const float4*)&As[k][ty * 4];
            float4 b = *(const float4*)&Bs[k][tx * 4];
            c[0][0] += a.x * b.x; c[0][1] += a.x * b.y; c[0][2] += a.x * b.z; c[0][3] += a.x * b.w;
            c[1][0] += a.y * b.x; c[1][1] += a.y * b.y; c[1][2] += a.y * b.z; c[1][3] += a.y * b.w;
            c[2][0] += a.z * b.x; c[2][1] += a.z * b.y; c[2][2] += a.z * b.z; c[2][3] += a.z * b.w;
            c[3][0] += a.w * b.x; c[3][1] += a.w * b.y; c[3][2] += a.w * b.z; c[3][3] += a.w * b.w;
        }
        __syncthreads();
    }

#pragma unroll
    for (int i = 0; i < 4; i++) {
        int mloc = ty * 4 + i;
        int n = n0 + tx * 4;
        if constexpr (MODE == 0) {
            size_t idx = (size_t)(blockIdx.y * 64 + mloc) * N + n;
            C[idx + 0] = c[i][0]; C[idx + 1] = c[i][1];
            C[idx + 2] = c[i][2]; C[idx + 3] = c[i][3];
        } else if constexpr (MODE == 1) {
            size_t idx = (size_t)(blockIdx.y * 64 + mloc) * N + n;
#pragma unroll
            for (int j = 0; j < 4; j++) C[idx + j] = resid[idx + j] + c[i][j] + bias[n + j];
        } else if constexpr (MODE == 2) {
            if (mloc < valid) {
                size_t idx = (size_t)(row0 + mloc) * N + n;
#pragma unroll
                for (int j = 0; j < 4; j++) C[idx + j] = gelu_exact(c[i][j] + bias[n + j]);
            }
        } else {  // MODE 3
            if (mloc < valid) {
                int t = perm[row0 + mloc];
                size_t idx = (size_t)t * N + n;
#pragma unroll
                for (int j = 0; j < 4; j++)
                    C[idx + j] = resid[idx + j] + gelu_exact(c[i][j] + bias[n + j]);
            }
        }
    }
}

extern "C" void kernel_launch(void* const* d_in, const int* in_sizes, int n_in,
                              void* d_out, int out_size, void* d_ws, size_t ws_size,
                              hipStream_t stream) {
    const float* x      = (const float*)d_in[0];
    // d_in[1] = indexes_list (unused, as in reference)
    const float* ln1_g  = (const float*)d_in[2];
    const float* ln1_b  = (const float*)d_in[3];
    const float* qkv_w  = (const float*)d_in[4];
    const float* proj_w = (const float*)d_in[5];
    const float* proj_b = (const float*)d_in[6];
    const float* ln2_g  = (const float*)d_in[7];
    const float* ln2_b  = (const float*)d_in[8];
    const float* sw     = (const float*)d_in[9];
    const float* sb     = (const float*)d_in[10];
    const float* w1     = (const float*)d_in[11];
    const float* b1     = (const float*)d_in[12];
    const float* w2     = (const float*)d_in[13];
    const float* b2     = (const float*)d_in[14];
    float* out = (float*)d_out;

    float* ws  = (float*)d_ws;
    float* h   = ws;                                   // T*D
    float* x1  = h + (size_t)T_TOK * D_MODEL;          // T*D
    float* big = x1 + (size_t)T_TOK * D_MODEL;
    float* qkv = big;                                  // T*3D
    float* y1  = big;                                  // (T + E*64)*FF grouped
    float* o   = out;                                  // attention out scratch
    int* ip        = (int*)(big + (size_t)(T_TOK + E_EXP * 64) * FF_DIM);
    int* routes    = ip;                    // 4096
    int* perm      = routes + T_TOK;        // 4608
    int* counts    = perm + T_TOK + E_EXP * 64;
    int* cursor    = counts + 8;
    int* pad_base  = cursor + 8;
    int* tile_e    = pad_base + 8;
    int* tile_row0 = tile_e + 80;
    int* tile_valid= tile_row0 + 80;
    int* ntiles    = tile_valid + 80;

    // 1. LN1: x -> h
    ln_kernel<<<T_TOK, 256, 0, stream>>>(x, ln1_g, ln1_b, h);
    // 2. QKV: h @ qkv_w -> qkv   [4096 x 2304, K=768]
    gemm64<0><<<dim3(2304 / 64, T_TOK / 64), 256, 0, stream>>>(
        h, qkv_w, nullptr, nullptr, qkv, 2304, 768,
        nullptr, nullptr, nullptr, nullptr, nullptr);
    // 3. Tiled flash attention: qkv -> o (d_out scratch)
    attn_tile<<<dim3(S_SEQ / 64, H_HEADS, B_BATCH), 256, 0, stream>>>(qkv, o);
    // 4. Proj + residual: x1 = x + o @ proj_w + proj_b   [4096 x 768, K=768]
    gemm64<1><<<dim3(768 / 64, T_TOK / 64), 256, 0, stream>>>(
        o, proj_w, proj_b, x, x1, 768, 768,
        nullptr, nullptr, nullptr, nullptr, nullptr);
    // 5. LN2: x1 -> h (reused)
    ln_kernel<<<T_TOK, 256, 0, stream>>>(x1, ln2_g, ln2_b, h);
    // 6-9. Routing
    zero_counts<<<1, 64, 0, stream>>>(counts, cursor);
    router_kernel<<<T_TOK, 64, 0, stream>>>(h, sw, sb, routes, counts);
    moe_plan<<<1, 1, 0, stream>>>(counts, pad_base, tile_e, tile_row0, tile_valid, ntiles);
    scatter_kernel<<<T_TOK / 256, 256, 0, stream>>>(routes, pad_base, cursor, perm);
    // 10. MoE up: y1[grouped] = gelu(h2[perm] @ w1[e] + b1[e])   [N=3072, K=768]
    gemm64<2><<<dim3(FF_DIM / 64, 72), 256, 0, stream>>>(
        h, w1, b1, nullptr, y1, FF_DIM, D_MODEL,
        perm, tile_e, tile_row0, tile_valid, ntiles);
    // 11. MoE down + residual scatter: out[t] = x1[t] + gelu(y1 @ w2[e] + b2[e])  [N=768, K=3072]
    gemm64<3><<<dim3(D_MODEL / 64, 72), 256, 0, stream>>>(
        y1, w2, b2, x1, out, D_MODEL, FF_DIM,
        perm, tile_e, tile_row0, tile_valid, ntiles);
}

// Round 4
// 872.206 us; speedup vs baseline: 2.8246x; 1.4683x over previous
//
#include <hip/hip_runtime.h>
#include <math.h>

// Problem constants
#define T_TOK   4096            // B*S
#define D_MODEL 768
#define H_HEADS 12
#define HDIM    64
#define S_SEQ   512
#define B_BATCH 8
#define E_EXP   8
#define FF_DIM  3072
#define GBK     16              // fp32 GEMM K-tile
#define MAX_TILES 40            // worst-case sum ceil(c_e/128)
#define MPAD_MAX  (MAX_TILES * 128)   // 5120

typedef __attribute__((ext_vector_type(8))) short short8;
typedef __attribute__((ext_vector_type(4))) float floatx4;

__device__ __forceinline__ float gelu_exact(float x) {
    return 0.5f * x * (1.0f + erff(x * 0.7071067811865476f));
}

// fp32 -> bf16 round-to-nearest-even
__device__ __forceinline__ unsigned short f2bf(float f) {
    unsigned int u = __float_as_uint(f);
    u += 0x7fffu + ((u >> 16) & 1u);
    return (unsigned short)(u >> 16);
}

// ---------------- LayerNorm (fp32): one block per token row ----------------
__global__ void __launch_bounds__(256) ln_kernel(const float* __restrict__ x,
                                                 const float* __restrict__ g,
                                                 const float* __restrict__ b,
                                                 float* __restrict__ out) {
    int row = blockIdx.x;
    const float* xr = x + (size_t)row * D_MODEL;
    int tid = threadIdx.x;
    float v0 = xr[tid];
    float v1 = xr[tid + 256];
    float v2 = xr[tid + 512];
    float s = v0 + v1 + v2;
    float q = v0 * v0 + v1 * v1 + v2 * v2;
    for (int off = 32; off; off >>= 1) {
        s += __shfl_down(s, off);
        q += __shfl_down(q, off);
    }
    __shared__ float rs[4], rq[4], stats[2];
    int wid = tid >> 6, lane = tid & 63;
    if (lane == 0) { rs[wid] = s; rq[wid] = q; }
    __syncthreads();
    if (tid == 0) {
        float ts = rs[0] + rs[1] + rs[2] + rs[3];
        float tq = rq[0] + rq[1] + rq[2] + rq[3];
        float mu = ts * (1.0f / 768.0f);
        float var = tq * (1.0f / 768.0f) - mu * mu;
        stats[0] = mu;
        stats[1] = rsqrtf(var + 1e-5f);
    }
    __syncthreads();
    float mu = stats[0], rstd = stats[1];
    float* orow = out + (size_t)row * D_MODEL;
    orow[tid]       = (v0 - mu) * rstd * g[tid]       + b[tid];
    orow[tid + 256] = (v1 - mu) * rstd * g[tid + 256] + b[tid + 256];
    orow[tid + 512] = (v2 - mu) * rstd * g[tid + 512] + b[tid + 512];
}

// ---------------- Weight transpose + fp32->bf16 ----------------
// in: [R][C] fp32 (batched by blockIdx.z); out: [C][R] bf16
__global__ void __launch_bounds__(256) transpose_bf16(const float* __restrict__ in,
                                                      unsigned short* __restrict__ out,
                                                      int R, int C) {
    __shared__ float t[32][33];
    const float* inb = in + (size_t)blockIdx.z * R * C;
    unsigned short* outb = out + (size_t)blockIdx.z * R * C;
    int c0 = blockIdx.x * 32, r0 = blockIdx.y * 32;
    int tx = threadIdx.x & 31, ty = threadIdx.x >> 5;   // ty 0..7
#pragma unroll
    for (int rr = 0; rr < 32; rr += 8)
        t[ty + rr][tx] = inb[(size_t)(r0 + ty + rr) * C + c0 + tx];
    __syncthreads();
#pragma unroll
    for (int rr = 0; rr < 32; rr += 8)
        outb[(size_t)(c0 + ty + rr) * R + r0 + tx] = f2bf(t[tx][ty + rr]);
}

// ---------------- Tiled flash attention (fp32 in/out) ----------------
__global__ void __launch_bounds__(256) attn_tile(const float* __restrict__ qkv,
                                                 float* __restrict__ o) {
    __shared__ float Qst[64][68];   // [d][r], pre-scaled by 1/8
    __shared__ float Kst[64][68];   // [d][c]; later aliased as Pst[key][row]
    __shared__ float Vs [64][68];   // [key][d]
    int qt = blockIdx.x, hh = blockIdx.y, bb = blockIdx.z;
    int tid = threadIdx.x;
    int tx = tid & 15, ty = tid >> 4;
    const size_t rstride = 3 * D_MODEL;
    const float* base = qkv + (size_t)bb * S_SEQ * rstride + hh * HDIM;

    {
        int f4 = tid & 15;
        int r0 = tid >> 4;
        for (int rr = 0; rr < 64; rr += 16) {
            int r = r0 + rr;
            const float* qrow = base + (size_t)(qt * 64 + r) * rstride;
            float4 v = *(const float4*)(qrow + f4 * 4);
            Qst[f4 * 4 + 0][r] = v.x * 0.125f;
            Qst[f4 * 4 + 1][r] = v.y * 0.125f;
            Qst[f4 * 4 + 2][r] = v.z * 0.125f;
            Qst[f4 * 4 + 3][r] = v.w * 0.125f;
        }
    }

    float m_run[4], l_run[4], o_acc[4][4];
#pragma unroll
    for (int i = 0; i < 4; i++) {
        m_run[i] = -1e30f; l_run[i] = 0.f;
#pragma unroll
        for (int j2 = 0; j2 < 4; j2++) o_acc[i][j2] = 0.f;
    }

    for (int kt = 0; kt < 8; kt++) {
        __syncthreads();
        {
            int f4 = tid & 15;
            int r0 = tid >> 4;
            for (int rr = 0; rr < 64; rr += 16) {
                int r = r0 + rr;
                const float* krow = base + (size_t)(kt * 64 + r) * rstride + D_MODEL;
                float4 v = *(const float4*)(krow + f4 * 4);
                Kst[f4 * 4 + 0][r] = v.x;
                Kst[f4 * 4 + 1][r] = v.y;
                Kst[f4 * 4 + 2][r] = v.z;
                Kst[f4 * 4 + 3][r] = v.w;
                const float* vrow = base + (size_t)(kt * 64 + r) * rstride + 2 * D_MODEL;
                *(float4*)&Vs[r][f4 * 4] = *(const float4*)(vrow + f4 * 4);
            }
        }
        __syncthreads();

        float s[4][4] = {};
#pragma unroll 8
        for (int d = 0; d < 64; d++) {
            float4 a = *(const float4*)&Qst[d][ty * 4];
            float4 b = *(const float4*)&Kst[d][tx * 4];
            s[0][0] += a.x * b.x; s[0][1] += a.x * b.y; s[0][2] += a.x * b.z; s[0][3] += a.x * b.w;
            s[1][0] += a.y * b.x; s[1][1] += a.y * b.y; s[1][2] += a.y * b.z; s[1][3] += a.y * b.w;
            s[2][0] += a.z * b.x; s[2][1] += a.z * b.y; s[2][2] += a.z * b.z; s[2][3] += a.z * b.w;
            s[3][0] += a.w * b.x; s[3][1] += a.w * b.y; s[3][2] += a.w * b.z; s[3][3] += a.w * b.w;
        }
        __syncthreads();

#pragma unroll
        for (int i = 0; i < 4; i++) {
            float tm = fmaxf(fmaxf(s[i][0], s[i][1]), fmaxf(s[i][2], s[i][3]));
            tm = fmaxf(tm, __shfl_xor(tm, 1));
            tm = fmaxf(tm, __shfl_xor(tm, 2));
            tm = fmaxf(tm, __shfl_xor(tm, 4));
            tm = fmaxf(tm, __shfl_xor(tm, 8));
            float mn = fmaxf(m_run[i], tm);
            float alpha = __expf(m_run[i] - mn);
            m_run[i] = mn;
            float ts = 0.f;
#pragma unroll
            for (int j2 = 0; j2 < 4; j2++) {
                s[i][j2] = __expf(s[i][j2] - mn);
                ts += s[i][j2];
            }
            ts += __shfl_xor(ts, 1);
            ts += __shfl_xor(ts, 2);
            ts += __shfl_xor(ts, 4);
            ts += __shfl_xor(ts, 8);
            l_run[i] = l_run[i] * alpha + ts;
#pragma unroll
            for (int j2 = 0; j2 < 4; j2++) o_acc[i][j2] *= alpha;
        }

#pragma unroll
        for (int i = 0; i < 4; i++)
#pragma unroll
            for (int j2 = 0; j2 < 4; j2++)
                Kst[tx * 4 + j2][ty * 4 + i] = s[i][j2];
        __syncthreads();

#pragma unroll 8
        for (int k = 0; k < 64; k++) {
            float4 a = *(const float4*)&Kst[k][ty * 4];
            float4 b = *(const float4*)&Vs[k][tx * 4];
            o_acc[0][0] += a.x * b.x; o_acc[0][1] += a.x * b.y; o_acc[0][2] += a.x * b.z; o_acc[0][3] += a.x * b.w;
            o_acc[1][0] += a.y * b.x; o_acc[1][1] += a.y * b.y; o_acc[1][2] += a.y * b.z; o_acc[1][3] += a.y * b.w;
            o_acc[2][0] += a.z * b.x; o_acc[2][1] += a.z * b.y; o_acc[2][2] += a.z * b.z; o_acc[2][3] += a.z * b.w;
            o_acc[3][0] += a.w * b.x; o_acc[3][1] += a.w * b.y; o_acc[3][2] += a.w * b.z; o_acc[3][3] += a.w * b.w;
        }
    }

    float* obase = o + (size_t)(bb * S_SEQ + qt * 64) * D_MODEL + hh * HDIM;
#pragma unroll
    for (int i = 0; i < 4; i++) {
        float inv = 1.0f / l_run[i];
        float4 r;
        r.x = o_acc[i][0] * inv;
        r.y = o_acc[i][1] * inv;
        r.z = o_acc[i][2] * inv;
        r.w = o_acc[i][3] * inv;
        *(float4*)(obase + (size_t)(ty * 4 + i) * D_MODEL + tx * 4) = r;
    }
}

// ---------------- Router (fp32, identical to R2-passing version) ----------
__global__ void __launch_bounds__(64) router_kernel(const float* __restrict__ h2,
                                                    const float* __restrict__ sw,
                                                    const float* __restrict__ sb,
                                                    int* __restrict__ routes,
                                                    int* __restrict__ counts) {
    int t = blockIdx.x;
    int lane = threadIdx.x;
    const float* hr = h2 + (size_t)t * D_MODEL;
    float acc[8] = {};
    for (int d = lane; d < D_MODEL; d += 64) {
        float hv = hr[d];
        const float* wr = sw + (size_t)d * 8;
#pragma unroll
        for (int e = 0; e < 8; e++) acc[e] += hv * wr[e];
    }
#pragma unroll
    for (int e = 0; e < 8; e++)
        for (int off = 32; off; off >>= 1) acc[e] += __shfl_down(acc[e], off);
    if (lane == 0) {
        int best = 0;
        float bv = acc[0] + sb[0];
#pragma unroll
        for (int e = 1; e < 8; e++) {
            float v = acc[e] + sb[e];
            if (v > bv) { bv = v; best = e; }
        }
        routes[t] = best;
        atomicAdd(&counts[best], 1);
    }
}

__global__ void __launch_bounds__(256) init_kernel(int* counts, int* cursor, int* perm) {
    int idx = blockIdx.x * 256 + threadIdx.x;
    if (idx < MPAD_MAX) perm[idx] = -1;
    if (idx < 8) { counts[idx] = 0; cursor[idx] = 0; }
}

// Padded (to 128) per-expert tile plan
__global__ void moe_plan(const int* __restrict__ counts, int* pad_base,
                         int* tile_e, int* tile_row0, int* ntiles) {
    if (threadIdx.x == 0 && blockIdx.x == 0) {
        int base = 0, nt = 0;
        for (int e = 0; e < E_EXP; e++) {
            pad_base[e] = base;
            int c = counts[e];
            int nte = (c + 127) >> 7;
            for (int j = 0; j < nte; j++) {
                tile_e[nt] = e;
                tile_row0[nt] = base + j * 128;
                nt++;
            }
            base += nte * 128;
        }
        ntiles[0] = nt;
    }
}

__global__ void __launch_bounds__(256) scatter_kernel(const int* __restrict__ routes,
                                                      const int* __restrict__ pad_base,
                                                      int* __restrict__ cursor,
                                                      int* __restrict__ perm) {
    int t = blockIdx.x * 256 + threadIdx.x;
    if (t < T_TOK) {
        int e = routes[t];
        int pos = atomicAdd(&cursor[e], 1);
        perm[pad_base[e] + pos] = t;
    }
}

// Gather h2 rows by perm into packed bf16 A for the MoE up-GEMM
__global__ void __launch_bounds__(256) gather_bf16(const float* __restrict__ h2,
                                                   const int* __restrict__ perm,
                                                   unsigned short* __restrict__ Ag) {
    int g = blockIdx.x;
    int row = perm[g];
    unsigned short* dst = Ag + (size_t)g * D_MODEL;
    if (row >= 0) {
        const float* src = h2 + (size_t)row * D_MODEL;
        for (int d = threadIdx.x; d < D_MODEL; d += 256) dst[d] = f2bf(src[d]);
    } else {
        for (int d = threadIdx.x; d < D_MODEL; d += 256) dst[d] = 0;
    }
}

// ---------------- fp32 GEMM (R2-verified), 64x64 tile ----------------------
// MODE 0: C = A@B             (QKV)
// MODE 1: C = resid + A@B + bias   (proj + residual)
template <int MODE>
__global__ void __launch_bounds__(256) gemm64(const float* __restrict__ A,
                                              const float* __restrict__ Bw,
                                              const float* __restrict__ bias,
                                              const float* __restrict__ resid,
                                              float* __restrict__ C, int N, int K) {
    __shared__ float As[GBK][68];
    __shared__ float Bs[GBK][64];

    int tid = threadIdx.x;
    int tx = tid & 15, ty = tid >> 4;
    int n0 = blockIdx.x * 64;
    int m_stage = tid >> 2;
    int k_stage = (tid & 3) * 4;
    const float* Arow = A + (size_t)(blockIdx.y * 64 + m_stage) * K;

    float c[4][4] = {};
    for (int k0 = 0; k0 < K; k0 += GBK) {
        float4 av = *(const float4*)(Arow + k0 + k_stage);
        As[k_stage + 0][m_stage] = av.x;
        As[k_stage + 1][m_stage] = av.y;
        As[k_stage + 2][m_stage] = av.z;
        As[k_stage + 3][m_stage] = av.w;
        int kb = tid >> 4;
        int nb = (tid & 15) * 4;
        *(float4*)&Bs[kb][nb] = *(const float4*)(Bw + (size_t)(k0 + kb) * N + n0 + nb);
        __syncthreads();
#pragma unroll
        for (int k = 0; k < GBK; k++) {
            float4 a = *(const float4*)&As[k][ty * 4];
            float4 b = *(const float4*)&Bs[k][tx * 4];
            c[0][0] += a.x * b.x; c[0][1] += a.x * b.y; c[0][2] += a.x * b.z; c[0][3] += a.x * b.w;
            c[1][0] += a.y * b.x; c[1][1] += a.y * b.y; c[1][2] += a.y * b.z; c[1][3] += a.y * b.w;
            c[2][0] += a.z * b.x; c[2][1] += a.z * b.y; c[2][2] += a.z * b.z; c[2][3] += a.z * b.w;
            c[3][0] += a.w * b.x; c[3][1] += a.w * b.y; c[3][2] += a.w * b.z; c[3][3] += a.w * b.w;
        }
        __syncthreads();
    }

#pragma unroll
    for (int i = 0; i < 4; i++) {
        int mloc = ty * 4 + i;
        int n = n0 + tx * 4;
        size_t idx = (size_t)(blockIdx.y * 64 + mloc) * N + n;
        if constexpr (MODE == 0) {
            C[idx + 0] = c[i][0]; C[idx + 1] = c[i][1];
            C[idx + 2] = c[i][2]; C[idx + 3] = c[i][3];
        } else {
#pragma unroll
            for (int j = 0; j < 4; j++) C[idx + j] = resid[idx + j] + c[i][j] + bias[n + j];
        }
    }
}

// ---------------- bf16 MFMA GEMM: 128x128 tile, BK=32, 4 waves -------------
// A: [M][K] bf16 row-major.  Bt: [N][K] bf16 (B transposed).  Acc fp32.
// MODE 2: Cb = bf16(gelu(A@B + bias_e))  (MoE up, grouped rows, pads written)
// MODE 3: Cf[t] = resid[t] + gelu(A@B + bias_e), t=perm[row]  (MoE down)
template <int MODE>
__global__ void __launch_bounds__(256) mgemm(const unsigned short* __restrict__ A,
                                             const unsigned short* __restrict__ Bt,
                                             const float* __restrict__ bias,
                                             const float* __restrict__ resid,
                                             float* __restrict__ Cf,
                                             unsigned short* __restrict__ Cb,
                                             int N, int K,
                                             const int* __restrict__ perm,
                                             const int* __restrict__ tile_e,
                                             const int* __restrict__ tile_row0,
                                             const int* __restrict__ ntiles) {
    // stride 40 elems = 80 B = 20 banks: frag ds_read_b128 lands 2-way (free)
    __shared__ __align__(16) short As[128][40];
    __shared__ __align__(16) short Bs[128][40];

    if ((int)blockIdx.y >= ntiles[0]) return;
    int e = tile_e[blockIdx.y];
    int row0 = tile_row0[blockIdx.y];
    Bt += (size_t)e * N * K;
    bias += (size_t)e * N;
    int n0 = blockIdx.x * 128;

    int tid = threadIdx.x;
    int lane = tid & 63, wid = tid >> 6;
    int wr0 = (wid >> 1) * 64, wc0 = (wid & 1) * 64;
    int lm = lane & 15, q8 = (lane >> 4) * 8;

    int sr = tid >> 2;              // 0..63
    int sc = (tid & 3) * 8;         // 0,8,16,24

    floatx4 acc[4][4];
#pragma unroll
    for (int i = 0; i < 4; i++)
#pragma unroll
        for (int j = 0; j < 4; j++) acc[i][j] = (floatx4){0.f, 0.f, 0.f, 0.f};

    const unsigned short* Abase = A + (size_t)row0 * K;
    const unsigned short* Bbase = Bt + (size_t)n0 * K;

    for (int k0 = 0; k0 < K; k0 += 32) {
        *(uint4*)&As[sr][sc]      = *(const uint4*)(Abase + (size_t)sr * K + k0 + sc);
        *(uint4*)&As[sr + 64][sc] = *(const uint4*)(Abase + (size_t)(sr + 64) * K + k0 + sc);
        *(uint4*)&Bs[sr][sc]      = *(const uint4*)(Bbase + (size_t)sr * K + k0 + sc);
        *(uint4*)&Bs[sr + 64][sc] = *(const uint4*)(Bbase + (size_t)(sr + 64) * K + k0 + sc);
        __syncthreads();

        short8 af[4], bfr[4];
#pragma unroll
        for (int i = 0; i < 4; i++)
            af[i] = *(const short8*)&As[wr0 + i * 16 + lm][q8];
#pragma unroll
        for (int j = 0; j < 4; j++)
            bfr[j] = *(const short8*)&Bs[wc0 + j * 16 + lm][q8];
#pragma unroll
        for (int i = 0; i < 4; i++)
#pragma unroll
            for (int j = 0; j < 4; j++)
                acc[i][j] = __builtin_amdgcn_mfma_f32_16x16x32_bf16(af[i], bfr[j], acc[i][j], 0, 0, 0);
        __syncthreads();
    }

    // C/D layout: col = lane&15, row = (lane>>4)*4 + reg  [m89]
    int q4 = (lane >> 4) * 4;
#pragma unroll
    for (int i = 0; i < 4; i++) {
#pragma unroll
        for (int j = 0; j < 4; j++) {
            int c = n0 + wc0 + j * 16 + lm;
#pragma unroll
            for (int reg = 0; reg < 4; reg++) {
                int rloc = wr0 + i * 16 + q4 + reg;
                float v = acc[i][j][reg];
                if constexpr (MODE == 2) {
                    Cb[(size_t)(row0 + rloc) * N + c] = f2bf(gelu_exact(v + bias[c]));
                } else {
                    int t = perm[row0 + rloc];
                    if (t >= 0) {
                        size_t idx = (size_t)t * N + c;
                        Cf[idx] = resid[idx] + gelu_exact(v + bias[c]);
                    }
                }
            }
        }
    }
}

extern "C" void kernel_launch(void* const* d_in, const int* in_sizes, int n_in,
                              void* d_out, int out_size, void* d_ws, size_t ws_size,
                              hipStream_t stream) {
    const float* x      = (const float*)d_in[0];
    const float* ln1_g  = (const float*)d_in[2];
    const float* ln1_b  = (const float*)d_in[3];
    const float* qkv_w  = (const float*)d_in[4];
    const float* proj_w = (const float*)d_in[5];
    const float* proj_b = (const float*)d_in[6];
    const float* ln2_g  = (const float*)d_in[7];
    const float* ln2_b  = (const float*)d_in[8];
    const float* sw     = (const float*)d_in[9];
    const float* sb     = (const float*)d_in[10];
    const float* w1     = (const float*)d_in[11];
    const float* b1     = (const float*)d_in[12];
    const float* w2     = (const float*)d_in[13];
    const float* b2     = (const float*)d_in[14];
    float* out = (float*)d_out;

    // ---- workspace layout ----
    char* p = (char*)d_ws;
    // union: qkv fp32 [4096][2304] (dead after attn)  /  y1 bf16 [5120][3072]
    float*          qkv = (float*)p;
    unsigned short* y1  = (unsigned short*)p;
    p += (size_t)T_TOK * 2304 * 4;                                    // 37.75 MB
    float* h  = (float*)p;  p += (size_t)T_TOK * D_MODEL * 4;         // 12.6 MB (ln1 out, then ln2 out)
    float* x1 = (float*)p;  p += (size_t)T_TOK * D_MODEL * 4;         // 12.6 MB
    unsigned short* Ag  = (unsigned short*)p; p += (size_t)MPAD_MAX * D_MODEL * 2;   // 7.9 MB
    unsigned short* w1t = (unsigned short*)p; p += (size_t)E_EXP * 3072 * 768 * 2;   // 37.75 MB
    unsigned short* w2t = (unsigned short*)p; p += (size_t)E_EXP * 768 * 3072 * 2;   // 37.75 MB
    int* routes    = (int*)p;
    int* perm      = routes + T_TOK;
    int* counts    = perm + MPAD_MAX;
    int* cursor    = counts + 8;
    int* pad_base  = cursor + 8;
    int* tile_e    = pad_base + 8;
    int* tile_row0 = tile_e + MAX_TILES;
    int* ntiles    = tile_row0 + MAX_TILES;
    float* o = out;     // attention-out scratch; fully overwritten by mgemm<3>

    // ---- MoE weight convert+transpose (w1: [E][768][3072] -> [E][3072][768]) ----
    transpose_bf16<<<dim3(3072 / 32, 768 / 32, 8), 256, 0, stream>>>(w1, w1t, 768, 3072);
    transpose_bf16<<<dim3(768 / 32, 3072 / 32, 8), 256, 0, stream>>>(w2, w2t, 3072, 768);

    // 1. LN1 -> fp32 h
    ln_kernel<<<T_TOK, 256, 0, stream>>>(x, ln1_g, ln1_b, h);
    // 2. QKV (fp32): h @ qkv_w -> qkv
    gemm64<0><<<dim3(2304 / 64, T_TOK / 64), 256, 0, stream>>>(h, qkv_w, nullptr, nullptr, qkv, 2304, 768);
    // 3. Attention (fp32) -> o
    attn_tile<<<dim3(S_SEQ / 64, H_HEADS, B_BATCH), 256, 0, stream>>>(qkv, o);
    // 4. Proj + residual (fp32): x1 = x + o@proj_w + proj_b
    gemm64<1><<<dim3(768 / 64, T_TOK / 64), 256, 0, stream>>>(o, proj_w, proj_b, x, x1, 768, 768);
    // 5. LN2 -> fp32 h (router path: exact, same as R2)
    ln_kernel<<<T_TOK, 256, 0, stream>>>(x1, ln2_g, ln2_b, h);
    // 6-9. Routing (fp32, identical to R2)
    init_kernel<<<(MPAD_MAX + 255) / 256, 256, 0, stream>>>(counts, cursor, perm);
    router_kernel<<<T_TOK, 64, 0, stream>>>(h, sw, sb, routes, counts);
    moe_plan<<<1, 1, 0, stream>>>(counts, pad_base, tile_e, tile_row0, ntiles);
    scatter_kernel<<<T_TOK / 256, 256, 0, stream>>>(routes, pad_base, cursor, perm);
    // 10. Gather routed rows -> packed bf16 A
    gather_bf16<<<MPAD_MAX, 256, 0, stream>>>(h, perm, Ag);
    // 11. MoE up (bf16 MFMA): y1 = bf16(gelu(Ag @ w1t[e] + b1[e]))   [N=3072, K=768]
    mgemm<2><<<dim3(FF_DIM / 128, MAX_TILES), 256, 0, stream>>>(
        Ag, w1t, b1, nullptr, nullptr, y1, FF_DIM, 768,
        perm, tile_e, tile_row0, ntiles);
    // 12. MoE down + residual scatter (bf16 MFMA): out[t] = x1[t] + gelu(y1 @ w2t[e] + b2[e])
    mgemm<3><<<dim3(D_MODEL / 128, MAX_TILES), 256, 0, stream>>>(
        y1, w2t, b2, x1, out, nullptr, D_MODEL, 3072,
        perm, tile_e, tile_row0, ntiles);
}

// Round 5
// 701.604 us; speedup vs baseline: 3.5114x; 1.2432x over previous
//
#include <hip/hip_runtime.h>
#include <math.h>

// Problem constants
#define T_TOK   4096            // B*S
#define D_MODEL 768
#define H_HEADS 12
#define HDIM    64
#define S_SEQ   512
#define B_BATCH 8
#define E_EXP   8
#define FF_DIM  3072
#define MAX_TILES 40            // worst-case sum ceil(c_e/128)
#define MPAD_MAX  (MAX_TILES * 128)   // 5120

typedef __attribute__((ext_vector_type(8))) short short8;
typedef __attribute__((ext_vector_type(4))) float floatx4;

__device__ __forceinline__ float gelu_exact(float x) {
    return 0.5f * x * (1.0f + erff(x * 0.7071067811865476f));
}

// fp32 -> bf16 round-to-nearest-even
__device__ __forceinline__ unsigned short f2bf(float f) {
    unsigned int u = __float_as_uint(f);
    u += 0x7fffu + ((u >> 16) & 1u);
    return (unsigned short)(u >> 16);
}
__device__ __forceinline__ float bf2f(unsigned short h) {
    return __uint_as_float(((unsigned int)h) << 16);
}
// exact two-term bf16 split: v ~= hi + lo, |v-hi-lo| <= 2^-18 |v|
__device__ __forceinline__ void split_bf(float v, unsigned short& hi, unsigned short& lo) {
    hi = f2bf(v);
    lo = f2bf(v - bf2f(hi));
}

// ---------------- LayerNorm fp32-out ----------------
__global__ void __launch_bounds__(256) ln_f32(const float* __restrict__ x,
                                              const float* __restrict__ g,
                                              const float* __restrict__ b,
                                              float* __restrict__ out) {
    int row = blockIdx.x;
    const float* xr = x + (size_t)row * D_MODEL;
    int tid = threadIdx.x;
    float v0 = xr[tid], v1 = xr[tid + 256], v2 = xr[tid + 512];
    float s = v0 + v1 + v2;
    float q = v0 * v0 + v1 * v1 + v2 * v2;
    for (int off = 32; off; off >>= 1) {
        s += __shfl_down(s, off);
        q += __shfl_down(q, off);
    }
    __shared__ float rs[4], rq[4], stats[2];
    int wid = tid >> 6, lane = tid & 63;
    if (lane == 0) { rs[wid] = s; rq[wid] = q; }
    __syncthreads();
    if (tid == 0) {
        float ts = rs[0] + rs[1] + rs[2] + rs[3];
        float tq = rq[0] + rq[1] + rq[2] + rq[3];
        float mu = ts * (1.0f / 768.0f);
        float var = tq * (1.0f / 768.0f) - mu * mu;
        stats[0] = mu; stats[1] = rsqrtf(var + 1e-5f);
    }
    __syncthreads();
    float mu = stats[0], rstd = stats[1];
    float* orow = out + (size_t)row * D_MODEL;
    orow[tid]       = (v0 - mu) * rstd * g[tid]       + b[tid];
    orow[tid + 256] = (v1 - mu) * rstd * g[tid + 256] + b[tid + 256];
    orow[tid + 512] = (v2 - mu) * rstd * g[tid + 512] + b[tid + 512];
}

// ---------------- LayerNorm split-bf16-out ----------------
__global__ void __launch_bounds__(256) ln_split(const float* __restrict__ x,
                                                const float* __restrict__ g,
                                                const float* __restrict__ b,
                                                unsigned short* __restrict__ ohi,
                                                unsigned short* __restrict__ olo) {
    int row = blockIdx.x;
    const float* xr = x + (size_t)row * D_MODEL;
    int tid = threadIdx.x;
    float v0 = xr[tid], v1 = xr[tid + 256], v2 = xr[tid + 512];
    float s = v0 + v1 + v2;
    float q = v0 * v0 + v1 * v1 + v2 * v2;
    for (int off = 32; off; off >>= 1) {
        s += __shfl_down(s, off);
        q += __shfl_down(q, off);
    }
    __shared__ float rs[4], rq[4], stats[2];
    int wid = tid >> 6, lane = tid & 63;
    if (lane == 0) { rs[wid] = s; rq[wid] = q; }
    __syncthreads();
    if (tid == 0) {
        float ts = rs[0] + rs[1] + rs[2] + rs[3];
        float tq = rq[0] + rq[1] + rq[2] + rq[3];
        float mu = ts * (1.0f / 768.0f);
        float var = tq * (1.0f / 768.0f) - mu * mu;
        stats[0] = mu; stats[1] = rsqrtf(var + 1e-5f);
    }
    __syncthreads();
    float mu = stats[0], rstd = stats[1];
    unsigned short* hr = ohi + (size_t)row * D_MODEL;
    unsigned short* lr = olo + (size_t)row * D_MODEL;
    float r0 = (v0 - mu) * rstd * g[tid]       + b[tid];
    float r1 = (v1 - mu) * rstd * g[tid + 256] + b[tid + 256];
    float r2 = (v2 - mu) * rstd * g[tid + 512] + b[tid + 512];
    unsigned short hi, lo;
    split_bf(r0, hi, lo); hr[tid] = hi;       lr[tid] = lo;
    split_bf(r1, hi, lo); hr[tid + 256] = hi; lr[tid + 256] = lo;
    split_bf(r2, hi, lo); hr[tid + 512] = hi; lr[tid + 512] = lo;
}

// ---------------- Weight transpose fp32 -> bf16 (single) ----------------
__global__ void __launch_bounds__(256) transpose_bf16(const float* __restrict__ in,
                                                      unsigned short* __restrict__ out,
                                                      int R, int C) {
    __shared__ float t[32][33];
    const float* inb = in + (size_t)blockIdx.z * R * C;
    unsigned short* outb = out + (size_t)blockIdx.z * R * C;
    int c0 = blockIdx.x * 32, r0 = blockIdx.y * 32;
    int tx = threadIdx.x & 31, ty = threadIdx.x >> 5;
#pragma unroll
    for (int rr = 0; rr < 32; rr += 8)
        t[ty + rr][tx] = inb[(size_t)(r0 + ty + rr) * C + c0 + tx];
    __syncthreads();
#pragma unroll
    for (int rr = 0; rr < 32; rr += 8)
        outb[(size_t)(c0 + ty + rr) * R + r0 + tx] = f2bf(t[tx][ty + rr]);
}

// ---------------- Weight transpose fp32 -> split bf16 (hi+lo) -------------
__global__ void __launch_bounds__(256) transpose_split(const float* __restrict__ in,
                                                       unsigned short* __restrict__ out_hi,
                                                       unsigned short* __restrict__ out_lo,
                                                       int R, int C) {
    __shared__ float t[32][33];
    int c0 = blockIdx.x * 32, r0 = blockIdx.y * 32;
    int tx = threadIdx.x & 31, ty = threadIdx.x >> 5;
#pragma unroll
    for (int rr = 0; rr < 32; rr += 8)
        t[ty + rr][tx] = in[(size_t)(r0 + ty + rr) * C + c0 + tx];
    __syncthreads();
#pragma unroll
    for (int rr = 0; rr < 32; rr += 8) {
        float v = t[tx][ty + rr];
        unsigned short hi, lo;
        split_bf(v, hi, lo);
        size_t idx = (size_t)(c0 + ty + rr) * R + r0 + tx;
        out_hi[idx] = hi;
        out_lo[idx] = lo;
    }
}

// ---------------- Tiled flash attention (fp32), split-bf16 output ---------
__global__ void __launch_bounds__(256) attn_tile(const float* __restrict__ qkv,
                                                 unsigned short* __restrict__ ohi,
                                                 unsigned short* __restrict__ olo) {
    __shared__ float Qst[64][68];
    __shared__ float Kst[64][68];   // later aliased as Pst[key][row]
    __shared__ float Vs [64][68];
    int qt = blockIdx.x, hh = blockIdx.y, bb = blockIdx.z;
    int tid = threadIdx.x;
    int tx = tid & 15, ty = tid >> 4;
    const size_t rstride = 3 * D_MODEL;
    const float* base = qkv + (size_t)bb * S_SEQ * rstride + hh * HDIM;

    {
        int f4 = tid & 15;
        int r0 = tid >> 4;
        for (int rr = 0; rr < 64; rr += 16) {
            int r = r0 + rr;
            const float* qrow = base + (size_t)(qt * 64 + r) * rstride;
            float4 v = *(const float4*)(qrow + f4 * 4);
            Qst[f4 * 4 + 0][r] = v.x * 0.125f;
            Qst[f4 * 4 + 1][r] = v.y * 0.125f;
            Qst[f4 * 4 + 2][r] = v.z * 0.125f;
            Qst[f4 * 4 + 3][r] = v.w * 0.125f;
        }
    }

    float m_run[4], l_run[4], o_acc[4][4];
#pragma unroll
    for (int i = 0; i < 4; i++) {
        m_run[i] = -1e30f; l_run[i] = 0.f;
#pragma unroll
        for (int j2 = 0; j2 < 4; j2++) o_acc[i][j2] = 0.f;
    }

    for (int kt = 0; kt < 8; kt++) {
        __syncthreads();
        {
            int f4 = tid & 15;
            int r0 = tid >> 4;
            for (int rr = 0; rr < 64; rr += 16) {
                int r = r0 + rr;
                const float* krow = base + (size_t)(kt * 64 + r) * rstride + D_MODEL;
                float4 v = *(const float4*)(krow + f4 * 4);
                Kst[f4 * 4 + 0][r] = v.x;
                Kst[f4 * 4 + 1][r] = v.y;
                Kst[f4 * 4 + 2][r] = v.z;
                Kst[f4 * 4 + 3][r] = v.w;
                const float* vrow = base + (size_t)(kt * 64 + r) * rstride + 2 * D_MODEL;
                *(float4*)&Vs[r][f4 * 4] = *(const float4*)(vrow + f4 * 4);
            }
        }
        __syncthreads();

        float s[4][4] = {};
#pragma unroll 8
        for (int d = 0; d < 64; d++) {
            float4 a = *(const float4*)&Qst[d][ty * 4];
            float4 b = *(const float4*)&Kst[d][tx * 4];
            s[0][0] += a.x * b.x; s[0][1] += a.x * b.y; s[0][2] += a.x * b.z; s[0][3] += a.x * b.w;
            s[1][0] += a.y * b.x; s[1][1] += a.y * b.y; s[1][2] += a.y * b.z; s[1][3] += a.y * b.w;
            s[2][0] += a.z * b.x; s[2][1] += a.z * b.y; s[2][2] += a.z * b.z; s[2][3] += a.z * b.w;
            s[3][0] += a.w * b.x; s[3][1] += a.w * b.y; s[3][2] += a.w * b.z; s[3][3] += a.w * b.w;
        }
        __syncthreads();

#pragma unroll
        for (int i = 0; i < 4; i++) {
            float tm = fmaxf(fmaxf(s[i][0], s[i][1]), fmaxf(s[i][2], s[i][3]));
            tm = fmaxf(tm, __shfl_xor(tm, 1));
            tm = fmaxf(tm, __shfl_xor(tm, 2));
            tm = fmaxf(tm, __shfl_xor(tm, 4));
            tm = fmaxf(tm, __shfl_xor(tm, 8));
            float mn = fmaxf(m_run[i], tm);
            float alpha = __expf(m_run[i] - mn);
            m_run[i] = mn;
            float ts = 0.f;
#pragma unroll
            for (int j2 = 0; j2 < 4; j2++) {
                s[i][j2] = __expf(s[i][j2] - mn);
                ts += s[i][j2];
            }
            ts += __shfl_xor(ts, 1);
            ts += __shfl_xor(ts, 2);
            ts += __shfl_xor(ts, 4);
            ts += __shfl_xor(ts, 8);
            l_run[i] = l_run[i] * alpha + ts;
#pragma unroll
            for (int j2 = 0; j2 < 4; j2++) o_acc[i][j2] *= alpha;
        }

#pragma unroll
        for (int i = 0; i < 4; i++)
#pragma unroll
            for (int j2 = 0; j2 < 4; j2++)
                Kst[tx * 4 + j2][ty * 4 + i] = s[i][j2];
        __syncthreads();

#pragma unroll 8
        for (int k = 0; k < 64; k++) {
            float4 a = *(const float4*)&Kst[k][ty * 4];
            float4 b = *(const float4*)&Vs[k][tx * 4];
            o_acc[0][0] += a.x * b.x; o_acc[0][1] += a.x * b.y; o_acc[0][2] += a.x * b.z; o_acc[0][3] += a.x * b.w;
            o_acc[1][0] += a.y * b.x; o_acc[1][1] += a.y * b.y; o_acc[1][2] += a.y * b.z; o_acc[1][3] += a.y * b.w;
            o_acc[2][0] += a.z * b.x; o_acc[2][1] += a.z * b.y; o_acc[2][2] += a.z * b.z; o_acc[2][3] += a.z * b.w;
            o_acc[3][0] += a.w * b.x; o_acc[3][1] += a.w * b.y; o_acc[3][2] += a.w * b.z; o_acc[3][3] += a.w * b.w;
        }
    }

    size_t ob = (size_t)(bb * S_SEQ + qt * 64) * D_MODEL + hh * HDIM;
#pragma unroll
    for (int i = 0; i < 4; i++) {
        float inv = 1.0f / l_run[i];
        ushort4 rh, rl;
        unsigned short hi, lo;
        split_bf(o_acc[i][0] * inv, hi, lo); rh.x = hi; rl.x = lo;
        split_bf(o_acc[i][1] * inv, hi, lo); rh.y = hi; rl.y = lo;
        split_bf(o_acc[i][2] * inv, hi, lo); rh.z = hi; rl.z = lo;
        split_bf(o_acc[i][3] * inv, hi, lo); rh.w = hi; rl.w = lo;
        size_t idx = ob + (size_t)(ty * 4 + i) * D_MODEL + tx * 4;
        *(ushort4*)(ohi + idx) = rh;
        *(ushort4*)(olo + idx) = rl;
    }
}

// ---------------- Router (fp32, exact — unchanged from R2/R4) -------------
__global__ void __launch_bounds__(64) router_kernel(const float* __restrict__ h2,
                                                    const float* __restrict__ sw,
                                                    const float* __restrict__ sb,
                                                    int* __restrict__ routes,
                                                    int* __restrict__ counts) {
    int t = blockIdx.x;
    int lane = threadIdx.x;
    const float* hr = h2 + (size_t)t * D_MODEL;
    float acc[8] = {};
    for (int d = lane; d < D_MODEL; d += 64) {
        float hv = hr[d];
        const float* wr = sw + (size_t)d * 8;
#pragma unroll
        for (int e = 0; e < 8; e++) acc[e] += hv * wr[e];
    }
#pragma unroll
    for (int e = 0; e < 8; e++)
        for (int off = 32; off; off >>= 1) acc[e] += __shfl_down(acc[e], off);
    if (lane == 0) {
        int best = 0;
        float bv = acc[0] + sb[0];
#pragma unroll
        for (int e = 1; e < 8; e++) {
            float v = acc[e] + sb[e];
            if (v > bv) { bv = v; best = e; }
        }
        routes[t] = best;
        atomicAdd(&counts[best], 1);
    }
}

__global__ void __launch_bounds__(256) init_kernel(int* counts, int* cursor, int* perm) {
    int idx = blockIdx.x * 256 + threadIdx.x;
    if (idx < MPAD_MAX) perm[idx] = -1;
    if (idx < 8) { counts[idx] = 0; cursor[idx] = 0; }
}

__global__ void moe_plan(const int* __restrict__ counts, int* pad_base,
                         int* tile_e, int* tile_row0, int* ntiles) {
    if (threadIdx.x == 0 && blockIdx.x == 0) {
        int base = 0, nt = 0;
        for (int e = 0; e < E_EXP; e++) {
            pad_base[e] = base;
            int c = counts[e];
            int nte = (c + 127) >> 7;
            for (int j = 0; j < nte; j++) {
                tile_e[nt] = e;
                tile_row0[nt] = base + j * 128;
                nt++;
            }
            base += nte * 128;
        }
        ntiles[0] = nt;
    }
}

__global__ void __launch_bounds__(256) scatter_kernel(const int* __restrict__ routes,
                                                      const int* __restrict__ pad_base,
                                                      int* __restrict__ cursor,
                                                      int* __restrict__ perm) {
    int t = blockIdx.x * 256 + threadIdx.x;
    if (t < T_TOK) {
        int e = routes[t];
        int pos = atomicAdd(&cursor[e], 1);
        perm[pad_base[e] + pos] = t;
    }
}

__global__ void __launch_bounds__(256) gather_bf16(const float* __restrict__ h2,
                                                   const int* __restrict__ perm,
                                                   unsigned short* __restrict__ Ag) {
    int g = blockIdx.x;
    int row = perm[g];
    unsigned short* dst = Ag + (size_t)g * D_MODEL;
    if (row >= 0) {
        const float* src = h2 + (size_t)row * D_MODEL;
        for (int d = threadIdx.x; d < D_MODEL; d += 256) dst[d] = f2bf(src[d]);
    } else {
        for (int d = threadIdx.x; d < D_MODEL; d += 256) dst[d] = 0;
    }
}

// ---------------- split-bf16 MFMA GEMM (fp32-class accuracy) ---------------
// C = (Ah+Al)@(Bh+Bl) dropping Al@Bl; error ~2^-18 relative.
// A*: [M][K] bf16.  Bt*: [N][K] bf16 (transposed weights).
// MODE 0: Cf = A@B            MODE 1: Cf = resid + A@B + bias
template <int MODE>
__global__ void __launch_bounds__(256) sgemm(const unsigned short* __restrict__ Ah_,
                                             const unsigned short* __restrict__ Al_,
                                             const unsigned short* __restrict__ Bh_,
                                             const unsigned short* __restrict__ Bl_,
                                             const float* __restrict__ bias,
                                             const float* __restrict__ resid,
                                             float* __restrict__ Cf,
                                             int N, int K) {
    __shared__ __align__(16) short Ah[128][40];
    __shared__ __align__(16) short Al[128][40];
    __shared__ __align__(16) short Bh[128][40];
    __shared__ __align__(16) short Bl[128][40];

    int row0 = blockIdx.y * 128, n0 = blockIdx.x * 128;
    int tid = threadIdx.x;
    int lane = tid & 63, wid = tid >> 6;
    int wr0 = (wid >> 1) * 64, wc0 = (wid & 1) * 64;
    int lm = lane & 15, q8 = (lane >> 4) * 8;
    int sr = tid >> 2;              // 0..63
    int sc = (tid & 3) * 8;         // 0,8,16,24

    floatx4 acc[4][4];
#pragma unroll
    for (int i = 0; i < 4; i++)
#pragma unroll
        for (int j = 0; j < 4; j++) acc[i][j] = (floatx4){0.f, 0.f, 0.f, 0.f};

    const unsigned short* Ahb = Ah_ + (size_t)row0 * K;
    const unsigned short* Alb = Al_ + (size_t)row0 * K;
    const unsigned short* Bhb = Bh_ + (size_t)n0 * K;
    const unsigned short* Blb = Bl_ + (size_t)n0 * K;

    for (int k0 = 0; k0 < K; k0 += 32) {
        *(uint4*)&Ah[sr][sc]      = *(const uint4*)(Ahb + (size_t)sr * K + k0 + sc);
        *(uint4*)&Ah[sr + 64][sc] = *(const uint4*)(Ahb + (size_t)(sr + 64) * K + k0 + sc);
        *(uint4*)&Al[sr][sc]      = *(const uint4*)(Alb + (size_t)sr * K + k0 + sc);
        *(uint4*)&Al[sr + 64][sc] = *(const uint4*)(Alb + (size_t)(sr + 64) * K + k0 + sc);
        *(uint4*)&Bh[sr][sc]      = *(const uint4*)(Bhb + (size_t)sr * K + k0 + sc);
        *(uint4*)&Bh[sr + 64][sc] = *(const uint4*)(Bhb + (size_t)(sr + 64) * K + k0 + sc);
        *(uint4*)&Bl[sr][sc]      = *(const uint4*)(Blb + (size_t)sr * K + k0 + sc);
        *(uint4*)&Bl[sr + 64][sc] = *(const uint4*)(Blb + (size_t)(sr + 64) * K + k0 + sc);
        __syncthreads();

        short8 ah[4], al[4], bh[4], bl[4];
#pragma unroll
        for (int i = 0; i < 4; i++) {
            ah[i] = *(const short8*)&Ah[wr0 + i * 16 + lm][q8];
            al[i] = *(const short8*)&Al[wr0 + i * 16 + lm][q8];
        }
#pragma unroll
        for (int j = 0; j < 4; j++) {
            bh[j] = *(const short8*)&Bh[wc0 + j * 16 + lm][q8];
            bl[j] = *(const short8*)&Bl[wc0 + j * 16 + lm][q8];
        }
#pragma unroll
        for (int i = 0; i < 4; i++)
#pragma unroll
            for (int j = 0; j < 4; j++) {
                acc[i][j] = __builtin_amdgcn_mfma_f32_16x16x32_bf16(ah[i], bh[j], acc[i][j], 0, 0, 0);
                acc[i][j] = __builtin_amdgcn_mfma_f32_16x16x32_bf16(ah[i], bl[j], acc[i][j], 0, 0, 0);
                acc[i][j] = __builtin_amdgcn_mfma_f32_16x16x32_bf16(al[i], bh[j], acc[i][j], 0, 0, 0);
            }
        __syncthreads();
    }

    // C/D layout: col = lane&15, row = (lane>>4)*4 + reg  [m89, R4-verified]
    int q4 = (lane >> 4) * 4;
#pragma unroll
    for (int i = 0; i < 4; i++) {
#pragma unroll
        for (int j = 0; j < 4; j++) {
            int c = n0 + wc0 + j * 16 + lm;
#pragma unroll
            for (int reg = 0; reg < 4; reg++) {
                int rloc = wr0 + i * 16 + q4 + reg;
                size_t idx = (size_t)(row0 + rloc) * N + c;
                float v = acc[i][j][reg];
                if constexpr (MODE == 0) Cf[idx] = v;
                else                     Cf[idx] = resid[idx] + v + bias[c];
            }
        }
    }
}

// ---------------- bf16 MFMA GEMM (MoE; R4-verified) ------------------------
// MODE 2: Cb = bf16(gelu(A@B + bias_e))   MODE 3: Cf[t]=resid[t]+gelu(A@B+bias_e)
template <int MODE>
__global__ void __launch_bounds__(256) mgemm(const unsigned short* __restrict__ A,
                                             const unsigned short* __restrict__ Bt,
                                             const float* __restrict__ bias,
                                             const float* __restrict__ resid,
                                             float* __restrict__ Cf,
                                             unsigned short* __restrict__ Cb,
                                             int N, int K,
                                             const int* __restrict__ perm,
                                             const int* __restrict__ tile_e,
                                             const int* __restrict__ tile_row0,
                                             const int* __restrict__ ntiles) {
    __shared__ __align__(16) short As[128][40];
    __shared__ __align__(16) short Bs[128][40];

    if ((int)blockIdx.y >= ntiles[0]) return;
    int e = tile_e[blockIdx.y];
    int row0 = tile_row0[blockIdx.y];
    Bt += (size_t)e * N * K;
    bias += (size_t)e * N;
    int n0 = blockIdx.x * 128;

    int tid = threadIdx.x;
    int lane = tid & 63, wid = tid >> 6;
    int wr0 = (wid >> 1) * 64, wc0 = (wid & 1) * 64;
    int lm = lane & 15, q8 = (lane >> 4) * 8;
    int sr = tid >> 2;
    int sc = (tid & 3) * 8;

    floatx4 acc[4][4];
#pragma unroll
    for (int i = 0; i < 4; i++)
#pragma unroll
        for (int j = 0; j < 4; j++) acc[i][j] = (floatx4){0.f, 0.f, 0.f, 0.f};

    const unsigned short* Abase = A + (size_t)row0 * K;
    const unsigned short* Bbase = Bt + (size_t)n0 * K;

    for (int k0 = 0; k0 < K; k0 += 32) {
        *(uint4*)&As[sr][sc]      = *(const uint4*)(Abase + (size_t)sr * K + k0 + sc);
        *(uint4*)&As[sr + 64][sc] = *(const uint4*)(Abase + (size_t)(sr + 64) * K + k0 + sc);
        *(uint4*)&Bs[sr][sc]      = *(const uint4*)(Bbase + (size_t)sr * K + k0 + sc);
        *(uint4*)&Bs[sr + 64][sc] = *(const uint4*)(Bbase + (size_t)(sr + 64) * K + k0 + sc);
        __syncthreads();

        short8 af[4], bfr[4];
#pragma unroll
        for (int i = 0; i < 4; i++)
            af[i] = *(const short8*)&As[wr0 + i * 16 + lm][q8];
#pragma unroll
        for (int j = 0; j < 4; j++)
            bfr[j] = *(const short8*)&Bs[wc0 + j * 16 + lm][q8];
#pragma unroll
        for (int i = 0; i < 4; i++)
#pragma unroll
            for (int j = 0; j < 4; j++)
                acc[i][j] = __builtin_amdgcn_mfma_f32_16x16x32_bf16(af[i], bfr[j], acc[i][j], 0, 0, 0);
        __syncthreads();
    }

    int q4 = (lane >> 4) * 4;
#pragma unroll
    for (int i = 0; i < 4; i++) {
#pragma unroll
        for (int j = 0; j < 4; j++) {
            int c = n0 + wc0 + j * 16 + lm;
#pragma unroll
            for (int reg = 0; reg < 4; reg++) {
                int rloc = wr0 + i * 16 + q4 + reg;
                float v = acc[i][j][reg];
                if constexpr (MODE == 2) {
                    Cb[(size_t)(row0 + rloc) * N + c] = f2bf(gelu_exact(v + bias[c]));
                } else {
                    int t = perm[row0 + rloc];
                    if (t >= 0) {
                        size_t idx = (size_t)t * N + c;
                        Cf[idx] = resid[idx] + gelu_exact(v + bias[c]);
                    }
                }
            }
        }
    }
}

extern "C" void kernel_launch(void* const* d_in, const int* in_sizes, int n_in,
                              void* d_out, int out_size, void* d_ws, size_t ws_size,
                              hipStream_t stream) {
    const float* x      = (const float*)d_in[0];
    const float* ln1_g  = (const float*)d_in[2];
    const float* ln1_b  = (const float*)d_in[3];
    const float* qkv_w  = (const float*)d_in[4];
    const float* proj_w = (const float*)d_in[5];
    const float* proj_b = (const float*)d_in[6];
    const float* ln2_g  = (const float*)d_in[7];
    const float* ln2_b  = (const float*)d_in[8];
    const float* sw     = (const float*)d_in[9];
    const float* sb     = (const float*)d_in[10];
    const float* w1     = (const float*)d_in[11];
    const float* b1     = (const float*)d_in[12];
    const float* w2     = (const float*)d_in[13];
    const float* b2     = (const float*)d_in[14];
    float* out = (float*)d_out;

    // ---- workspace layout ----
    // "big" union (37.75 MB): qkv fp32 [steps 2-3] / h fp32 LN2-out [5-11] / y1 bf16 [12-13]
    char* p = (char*)d_ws;
    float*          qkv = (float*)p;
    float*          h   = (float*)p;
    unsigned short* y1  = (unsigned short*)p;
    p += (size_t)T_TOK * 2304 * 4;
    // h_hi/h_lo (LN1-out, dead after QKV) alias o_hi/o_lo (attn-out)
    unsigned short* h_hi = (unsigned short*)p; p += (size_t)T_TOK * D_MODEL * 2;
    unsigned short* h_lo = (unsigned short*)p; p += (size_t)T_TOK * D_MODEL * 2;
    unsigned short* o_hi = h_hi;
    unsigned short* o_lo = h_lo;
    float* x1 = (float*)p; p += (size_t)T_TOK * D_MODEL * 4;
    // Ag (7.86 MB) union qkv weight splits (7.08 MB): wt dead after step 6, Ag written step 11
    unsigned short* Ag     = (unsigned short*)p;
    unsigned short* qwt_hi = (unsigned short*)p;
    unsigned short* qwt_lo = qwt_hi + (size_t)2304 * 768;
    p += (size_t)MPAD_MAX * D_MODEL * 2;
    unsigned short* pwt_hi = (unsigned short*)p; p += (size_t)768 * 768 * 2;
    unsigned short* pwt_lo = (unsigned short*)p; p += (size_t)768 * 768 * 2;
    unsigned short* w1t = (unsigned short*)p; p += (size_t)E_EXP * 3072 * 768 * 2;
    unsigned short* w2t = (unsigned short*)p; p += (size_t)E_EXP * 768 * 3072 * 2;
    int* routes    = (int*)p;
    int* perm      = routes + T_TOK;
    int* counts    = perm + MPAD_MAX;
    int* cursor    = counts + 8;
    int* pad_base  = cursor + 8;
    int* tile_e    = pad_base + 8;
    int* tile_row0 = tile_e + MAX_TILES;
    int* ntiles    = tile_row0 + MAX_TILES;

    // ---- weight preprocessing ----
    transpose_split<<<dim3(2304 / 32, 768 / 32), 256, 0, stream>>>(qkv_w, qwt_hi, qwt_lo, 768, 2304);
    transpose_split<<<dim3(768 / 32, 768 / 32), 256, 0, stream>>>(proj_w, pwt_hi, pwt_lo, 768, 768);
    transpose_bf16<<<dim3(3072 / 32, 768 / 32, 8), 256, 0, stream>>>(w1, w1t, 768, 3072);
    transpose_bf16<<<dim3(768 / 32, 3072 / 32, 8), 256, 0, stream>>>(w2, w2t, 3072, 768);

    // 1. LN1 -> split bf16 (h_hi, h_lo)
    ln_split<<<T_TOK, 256, 0, stream>>>(x, ln1_g, ln1_b, h_hi, h_lo);
    // 2. QKV (split-bf16 MFMA): qkv = h @ qkv_w   [4096 x 2304, K=768]
    sgemm<0><<<dim3(2304 / 128, T_TOK / 128), 256, 0, stream>>>(
        h_hi, h_lo, qwt_hi, qwt_lo, nullptr, nullptr, qkv, 2304, 768);
    // 3. Attention (fp32) -> split bf16 o
    attn_tile<<<dim3(S_SEQ / 64, H_HEADS, B_BATCH), 256, 0, stream>>>(qkv, o_hi, o_lo);
    // 4. Proj + residual (split-bf16 MFMA): x1 = x + o@proj_w + proj_b
    sgemm<1><<<dim3(768 / 128, T_TOK / 128), 256, 0, stream>>>(
        o_hi, o_lo, pwt_hi, pwt_lo, proj_b, x, x1, 768, 768);
    // 5. LN2 -> fp32 h (router path: exact fp32)
    ln_f32<<<T_TOK, 256, 0, stream>>>(x1, ln2_g, ln2_b, h);
    // 6-9. Routing (fp32, unchanged)
    init_kernel<<<(MPAD_MAX + 255) / 256, 256, 0, stream>>>(counts, cursor, perm);
    router_kernel<<<T_TOK, 64, 0, stream>>>(h, sw, sb, routes, counts);
    moe_plan<<<1, 1, 0, stream>>>(counts, pad_base, tile_e, tile_row0, ntiles);
    scatter_kernel<<<T_TOK / 256, 256, 0, stream>>>(routes, pad_base, cursor, perm);
    // 10. Gather routed rows -> packed bf16 A
    gather_bf16<<<MPAD_MAX, 256, 0, stream>>>(h, perm, Ag);
    // 11. MoE up (bf16 MFMA): y1 = bf16(gelu(Ag @ w1t[e] + b1[e]))
    mgemm<2><<<dim3(FF_DIM / 128, MAX_TILES), 256, 0, stream>>>(
        Ag, w1t, b1, nullptr, nullptr, y1, FF_DIM, 768,
        perm, tile_e, tile_row0, ntiles);
    // 12. MoE down + residual scatter (bf16 MFMA)
    mgemm<3><<<dim3(D_MODEL / 128, MAX_TILES), 256, 0, stream>>>(
        y1, w2t, b2, x1, out, nullptr, D_MODEL, 3072,
        perm, tile_e, tile_row0, ntiles);
}

// Round 6
// 650.942 us; speedup vs baseline: 3.7847x; 1.0778x over previous
//
#include <hip/hip_runtime.h>
#include <math.h>

// Problem constants
#define T_TOK   4096            // B*S
#define D_MODEL 768
#define H_HEADS 12
#define HDIM    64
#define S_SEQ   512
#define B_BATCH 8
#define E_EXP   8
#define FF_DIM  3072
#define MAX_TILES 40            // worst-case sum ceil(c_e/128)
#define MPAD_MAX  (MAX_TILES * 128)   // 5120

typedef __attribute__((ext_vector_type(8))) short short8;
typedef __attribute__((ext_vector_type(4))) float floatx4;

__device__ __forceinline__ float gelu_exact(float x) {
    return 0.5f * x * (1.0f + erff(x * 0.7071067811865476f));
}

// fp32 -> bf16 round-to-nearest-even
__device__ __forceinline__ unsigned short f2bf(float f) {
    unsigned int u = __float_as_uint(f);
    u += 0x7fffu + ((u >> 16) & 1u);
    return (unsigned short)(u >> 16);
}
__device__ __forceinline__ float bf2f(unsigned short h) {
    return __uint_as_float(((unsigned int)h) << 16);
}
// exact two-term bf16 split: v ~= hi + lo, |v-hi-lo| <= 2^-18 |v|
__device__ __forceinline__ void split_bf(float v, unsigned short& hi, unsigned short& lo) {
    hi = f2bf(v);
    lo = f2bf(v - bf2f(hi));
}

// ---------------- LayerNorm fp32-out ----------------
__global__ void __launch_bounds__(256) ln_f32(const float* __restrict__ x,
                                              const float* __restrict__ g,
                                              const float* __restrict__ b,
                                              float* __restrict__ out) {
    int row = blockIdx.x;
    const float* xr = x + (size_t)row * D_MODEL;
    int tid = threadIdx.x;
    float v0 = xr[tid], v1 = xr[tid + 256], v2 = xr[tid + 512];
    float s = v0 + v1 + v2;
    float q = v0 * v0 + v1 * v1 + v2 * v2;
    for (int off = 32; off; off >>= 1) {
        s += __shfl_down(s, off);
        q += __shfl_down(q, off);
    }
    __shared__ float rs[4], rq[4], stats[2];
    int wid = tid >> 6, lane = tid & 63;
    if (lane == 0) { rs[wid] = s; rq[wid] = q; }
    __syncthreads();
    if (tid == 0) {
        float ts = rs[0] + rs[1] + rs[2] + rs[3];
        float tq = rq[0] + rq[1] + rq[2] + rq[3];
        float mu = ts * (1.0f / 768.0f);
        float var = tq * (1.0f / 768.0f) - mu * mu;
        stats[0] = mu; stats[1] = rsqrtf(var + 1e-5f);
    }
    __syncthreads();
    float mu = stats[0], rstd = stats[1];
    float* orow = out + (size_t)row * D_MODEL;
    orow[tid]       = (v0 - mu) * rstd * g[tid]       + b[tid];
    orow[tid + 256] = (v1 - mu) * rstd * g[tid + 256] + b[tid + 256];
    orow[tid + 512] = (v2 - mu) * rstd * g[tid + 512] + b[tid + 512];
}

// ---------------- LayerNorm split-bf16-out ----------------
__global__ void __launch_bounds__(256) ln_split(const float* __restrict__ x,
                                                const float* __restrict__ g,
                                                const float* __restrict__ b,
                                                unsigned short* __restrict__ ohi,
                                                unsigned short* __restrict__ olo) {
    int row = blockIdx.x;
    const float* xr = x + (size_t)row * D_MODEL;
    int tid = threadIdx.x;
    float v0 = xr[tid], v1 = xr[tid + 256], v2 = xr[tid + 512];
    float s = v0 + v1 + v2;
    float q = v0 * v0 + v1 * v1 + v2 * v2;
    for (int off = 32; off; off >>= 1) {
        s += __shfl_down(s, off);
        q += __shfl_down(q, off);
    }
    __shared__ float rs[4], rq[4], stats[2];
    int wid = tid >> 6, lane = tid & 63;
    if (lane == 0) { rs[wid] = s; rq[wid] = q; }
    __syncthreads();
    if (tid == 0) {
        float ts = rs[0] + rs[1] + rs[2] + rs[3];
        float tq = rq[0] + rq[1] + rq[2] + rq[3];
        float mu = ts * (1.0f / 768.0f);
        float var = tq * (1.0f / 768.0f) - mu * mu;
        stats[0] = mu; stats[1] = rsqrtf(var + 1e-5f);
    }
    __syncthreads();
    float mu = stats[0], rstd = stats[1];
    unsigned short* hr = ohi + (size_t)row * D_MODEL;
    unsigned short* lr = olo + (size_t)row * D_MODEL;
    float r0 = (v0 - mu) * rstd * g[tid]       + b[tid];
    float r1 = (v1 - mu) * rstd * g[tid + 256] + b[tid + 256];
    float r2 = (v2 - mu) * rstd * g[tid + 512] + b[tid + 512];
    unsigned short hi, lo;
    split_bf(r0, hi, lo); hr[tid] = hi;       lr[tid] = lo;
    split_bf(r1, hi, lo); hr[tid + 256] = hi; lr[tid + 256] = lo;
    split_bf(r2, hi, lo); hr[tid + 512] = hi; lr[tid + 512] = lo;
}

// ---------------- Weight transpose fp32 -> bf16 (single) ----------------
__global__ void __launch_bounds__(256) transpose_bf16(const float* __restrict__ in,
                                                      unsigned short* __restrict__ out,
                                                      int R, int C) {
    __shared__ float t[32][33];
    const float* inb = in + (size_t)blockIdx.z * R * C;
    unsigned short* outb = out + (size_t)blockIdx.z * R * C;
    int c0 = blockIdx.x * 32, r0 = blockIdx.y * 32;
    int tx = threadIdx.x & 31, ty = threadIdx.x >> 5;
#pragma unroll
    for (int rr = 0; rr < 32; rr += 8)
        t[ty + rr][tx] = inb[(size_t)(r0 + ty + rr) * C + c0 + tx];
    __syncthreads();
#pragma unroll
    for (int rr = 0; rr < 32; rr += 8)
        outb[(size_t)(c0 + ty + rr) * R + r0 + tx] = f2bf(t[tx][ty + rr]);
}

// ---------------- Weight transpose fp32 -> split bf16 (hi+lo) -------------
__global__ void __launch_bounds__(256) transpose_split(const float* __restrict__ in,
                                                       unsigned short* __restrict__ out_hi,
                                                       unsigned short* __restrict__ out_lo,
                                                       int R, int C) {
    __shared__ float t[32][33];
    int c0 = blockIdx.x * 32, r0 = blockIdx.y * 32;
    int tx = threadIdx.x & 31, ty = threadIdx.x >> 5;
#pragma unroll
    for (int rr = 0; rr < 32; rr += 8)
        t[ty + rr][tx] = in[(size_t)(r0 + ty + rr) * C + c0 + tx];
    __syncthreads();
#pragma unroll
    for (int rr = 0; rr < 32; rr += 8) {
        float v = t[tx][ty + rr];
        unsigned short hi, lo;
        split_bf(v, hi, lo);
        size_t idx = (size_t)(c0 + ty + rr) * R + r0 + tx;
        out_hi[idx] = hi;
        out_lo[idx] = lo;
    }
}

// ---------------- MFMA flash attention (split-bf16, fp32-class accuracy) --
// One block per (64-row q-tile, head, batch). 4 waves; wave w owns S/O rows
// [16w,16w+16). Q A-frags live in registers (loaded once). K buffers are
// aliased as P after the S phase. V staged transposed [d][key].
// LDS 4*64*72*2 = 36.9 KB -> 4 blocks/CU capacity; stride 72 shorts = 144 B
// keeps ds_read_b128 16B-aligned, start banks 4*lm mod 32 -> 2-way (free).
__global__ void __launch_bounds__(256) attn_mfma(const float* __restrict__ qkv,
                                                 unsigned short* __restrict__ ohi,
                                                 unsigned short* __restrict__ olo) {
    __shared__ __align__(16) short Kh[64][72], Kl[64][72];   // S: K ; PV: P
    __shared__ __align__(16) short Vh[64][72], Vl[64][72];   // V^T: [d][key]

    int qt = blockIdx.x, hh = blockIdx.y, bb = blockIdx.z;
    int tid = threadIdx.x;
    int lane = tid & 63, wv = tid >> 6;
    int lm = lane & 15, q8 = (lane >> 4) * 8, q4 = (lane >> 4) * 4;
    const size_t rstride = 3 * D_MODEL;
    const float* base = qkv + (size_t)bb * S_SEQ * rstride + hh * HDIM;

    // --- Q A-frags (scaled 1/8, split) directly global->registers ---
    short8 qh[2], ql[2];
    {
        const float* qrow = base + (size_t)(qt * 64 + 16 * wv + lm) * rstride;
#pragma unroll
        for (int ks = 0; ks < 2; ks++) {
            float4 v0 = *(const float4*)(qrow + ks * 32 + q8);
            float4 v1 = *(const float4*)(qrow + ks * 32 + q8 + 4);
            unsigned short h_, l_;
            short8 sh, sl;
            split_bf(v0.x * 0.125f, h_, l_); sh[0] = (short)h_; sl[0] = (short)l_;
            split_bf(v0.y * 0.125f, h_, l_); sh[1] = (short)h_; sl[1] = (short)l_;
            split_bf(v0.z * 0.125f, h_, l_); sh[2] = (short)h_; sl[2] = (short)l_;
            split_bf(v0.w * 0.125f, h_, l_); sh[3] = (short)h_; sl[3] = (short)l_;
            split_bf(v1.x * 0.125f, h_, l_); sh[4] = (short)h_; sl[4] = (short)l_;
            split_bf(v1.y * 0.125f, h_, l_); sh[5] = (short)h_; sl[5] = (short)l_;
            split_bf(v1.z * 0.125f, h_, l_); sh[6] = (short)h_; sl[6] = (short)l_;
            split_bf(v1.w * 0.125f, h_, l_); sh[7] = (short)h_; sl[7] = (short)l_;
            qh[ks] = sh; ql[ks] = sl;
        }
    }

    float m_run[4], l_run[4];
    floatx4 o_acc[4];
#pragma unroll
    for (int i = 0; i < 4; i++) {
        m_run[i] = -1e30f; l_run[i] = 0.f;
        o_acc[i] = (floatx4){0.f, 0.f, 0.f, 0.f};
    }

    int sr = tid >> 2;              // staging row 0..63
    int sc0 = (tid & 3) * 16;       // staging dim block

    for (int kt = 0; kt < 8; kt++) {
        __syncthreads();   // A: prev PV frag reads done
        {
            const float* krow = base + (size_t)(kt * 64 + sr) * rstride + D_MODEL;
            const float* vrow = krow + D_MODEL;
#pragma unroll
            for (int c = 0; c < 16; c += 4) {
                float4 kv = *(const float4*)(krow + sc0 + c);
                ushort4 h4, l4; unsigned short h_, l_;
                split_bf(kv.x, h_, l_); h4.x = h_; l4.x = l_;
                split_bf(kv.y, h_, l_); h4.y = h_; l4.y = l_;
                split_bf(kv.z, h_, l_); h4.z = h_; l4.z = l_;
                split_bf(kv.w, h_, l_); h4.w = h_; l4.w = l_;
                *(ushort4*)&Kh[sr][sc0 + c] = h4;
                *(ushort4*)&Kl[sr][sc0 + c] = l4;
                float4 vv = *(const float4*)(vrow + sc0 + c);
                split_bf(vv.x, h_, l_); Vh[sc0 + c + 0][sr] = (short)h_; Vl[sc0 + c + 0][sr] = (short)l_;
                split_bf(vv.y, h_, l_); Vh[sc0 + c + 1][sr] = (short)h_; Vl[sc0 + c + 1][sr] = (short)l_;
                split_bf(vv.z, h_, l_); Vh[sc0 + c + 2][sr] = (short)h_; Vl[sc0 + c + 2][sr] = (short)l_;
                split_bf(vv.w, h_, l_); Vh[sc0 + c + 3][sr] = (short)h_; Vl[sc0 + c + 3][sr] = (short)l_;
            }
        }
        __syncthreads();   // B: staging visible

        // S = Q @ K^T (3-term split)
        floatx4 s_acc[4];
#pragma unroll
        for (int nt = 0; nt < 4; nt++) s_acc[nt] = (floatx4){0.f, 0.f, 0.f, 0.f};
#pragma unroll
        for (int ks = 0; ks < 2; ks++) {
#pragma unroll
            for (int nt = 0; nt < 4; nt++) {
                short8 bh = *(const short8*)&Kh[nt * 16 + lm][ks * 32 + q8];
                short8 bl = *(const short8*)&Kl[nt * 16 + lm][ks * 32 + q8];
                s_acc[nt] = __builtin_amdgcn_mfma_f32_16x16x32_bf16(qh[ks], bh, s_acc[nt], 0, 0, 0);
                s_acc[nt] = __builtin_amdgcn_mfma_f32_16x16x32_bf16(qh[ks], bl, s_acc[nt], 0, 0, 0);
                s_acc[nt] = __builtin_amdgcn_mfma_f32_16x16x32_bf16(ql[ks], bh, s_acc[nt], 0, 0, 0);
            }
        }

        // Online softmax (C-layout: col=lane&15, row=q4+reg; row reduce = 16-lane quad)
        float alpha_r[4];
#pragma unroll
        for (int reg = 0; reg < 4; reg++) {
            float tm = fmaxf(fmaxf(s_acc[0][reg], s_acc[1][reg]),
                             fmaxf(s_acc[2][reg], s_acc[3][reg]));
            tm = fmaxf(tm, __shfl_xor(tm, 1));
            tm = fmaxf(tm, __shfl_xor(tm, 2));
            tm = fmaxf(tm, __shfl_xor(tm, 4));
            tm = fmaxf(tm, __shfl_xor(tm, 8));
            float mn = fmaxf(m_run[reg], tm);
            alpha_r[reg] = __expf(m_run[reg] - mn);
            m_run[reg] = mn;
            float ts = 0.f;
#pragma unroll
            for (int nt = 0; nt < 4; nt++) {
                float pv = __expf(s_acc[nt][reg] - mn);
                s_acc[nt][reg] = pv;
                ts += pv;
            }
            ts += __shfl_xor(ts, 1);
            ts += __shfl_xor(ts, 2);
            ts += __shfl_xor(ts, 4);
            ts += __shfl_xor(ts, 8);
            l_run[reg] = l_run[reg] * alpha_r[reg] + ts;
        }

        __syncthreads();   // C: all S frag reads of Kh/Kl retired -> safe to overwrite as P

        // P (split) into the K buffers: P[row][key]
#pragma unroll
        for (int nt = 0; nt < 4; nt++)
#pragma unroll
            for (int reg = 0; reg < 4; reg++) {
                unsigned short h_, l_;
                split_bf(s_acc[nt][reg], h_, l_);
                Kh[16 * wv + q4 + reg][nt * 16 + lm] = (short)h_;
                Kl[16 * wv + q4 + reg][nt * 16 + lm] = (short)l_;
            }
        // rescale O accumulator
#pragma unroll
        for (int nt = 0; nt < 4; nt++)
#pragma unroll
            for (int reg = 0; reg < 4; reg++) o_acc[nt][reg] *= alpha_r[reg];

        __syncthreads();   // D: P visible

        // O += P @ V (3-term split); A = P[m][key], B = V^T[d][key] n-major
#pragma unroll
        for (int ks = 0; ks < 2; ks++) {
            short8 ph = *(const short8*)&Kh[16 * wv + lm][ks * 32 + q8];
            short8 pl = *(const short8*)&Kl[16 * wv + lm][ks * 32 + q8];
#pragma unroll
            for (int nt = 0; nt < 4; nt++) {
                short8 vh = *(const short8*)&Vh[nt * 16 + lm][ks * 32 + q8];
                short8 vl = *(const short8*)&Vl[nt * 16 + lm][ks * 32 + q8];
                o_acc[nt] = __builtin_amdgcn_mfma_f32_16x16x32_bf16(ph, vh, o_acc[nt], 0, 0, 0);
                o_acc[nt] = __builtin_amdgcn_mfma_f32_16x16x32_bf16(ph, vl, o_acc[nt], 0, 0, 0);
                o_acc[nt] = __builtin_amdgcn_mfma_f32_16x16x32_bf16(pl, vh, o_acc[nt], 0, 0, 0);
            }
        }
    }

    // Epilogue: O/l -> split hi/lo (C-layout scatter)
    size_t ob = (size_t)(bb * S_SEQ + qt * 64) * D_MODEL + hh * HDIM;
#pragma unroll
    for (int reg = 0; reg < 4; reg++) {
        float inv = 1.0f / l_run[reg];
#pragma unroll
        for (int nt = 0; nt < 4; nt++) {
            unsigned short h_, l_;
            split_bf(o_acc[nt][reg] * inv, h_, l_);
            size_t idx = ob + (size_t)(16 * wv + q4 + reg) * D_MODEL + nt * 16 + lm;
            ohi[idx] = h_;
            olo[idx] = l_;
        }
    }
}

// ---------------- Router (fp32, exact — unchanged) -------------
__global__ void __launch_bounds__(64) router_kernel(const float* __restrict__ h2,
                                                    const float* __restrict__ sw,
                                                    const float* __restrict__ sb,
                                                    int* __restrict__ routes,
                                                    int* __restrict__ counts) {
    int t = blockIdx.x;
    int lane = threadIdx.x;
    const float* hr = h2 + (size_t)t * D_MODEL;
    float acc[8] = {};
    for (int d = lane; d < D_MODEL; d += 64) {
        float hv = hr[d];
        const float* wr = sw + (size_t)d * 8;
#pragma unroll
        for (int e = 0; e < 8; e++) acc[e] += hv * wr[e];
    }
#pragma unroll
    for (int e = 0; e < 8; e++)
        for (int off = 32; off; off >>= 1) acc[e] += __shfl_down(acc[e], off);
    if (lane == 0) {
        int best = 0;
        float bv = acc[0] + sb[0];
#pragma unroll
        for (int e = 1; e < 8; e++) {
            float v = acc[e] + sb[e];
            if (v > bv) { bv = v; best = e; }
        }
        routes[t] = best;
        atomicAdd(&counts[best], 1);
    }
}

__global__ void __launch_bounds__(256) init_kernel(int* counts, int* cursor, int* perm) {
    int idx = blockIdx.x * 256 + threadIdx.x;
    if (idx < MPAD_MAX) perm[idx] = -1;
    if (idx < 8) { counts[idx] = 0; cursor[idx] = 0; }
}

__global__ void moe_plan(const int* __restrict__ counts, int* pad_base,
                         int* tile_e, int* tile_row0, int* ntiles) {
    if (threadIdx.x == 0 && blockIdx.x == 0) {
        int base = 0, nt = 0;
        for (int e = 0; e < E_EXP; e++) {
            pad_base[e] = base;
            int c = counts[e];
            int nte = (c + 127) >> 7;
            for (int j = 0; j < nte; j++) {
                tile_e[nt] = e;
                tile_row0[nt] = base + j * 128;
                nt++;
            }
            base += nte * 128;
        }
        ntiles[0] = nt;
    }
}

__global__ void __launch_bounds__(256) scatter_kernel(const int* __restrict__ routes,
                                                      const int* __restrict__ pad_base,
                                                      int* __restrict__ cursor,
                                                      int* __restrict__ perm) {
    int t = blockIdx.x * 256 + threadIdx.x;
    if (t < T_TOK) {
        int e = routes[t];
        int pos = atomicAdd(&cursor[e], 1);
        perm[pad_base[e] + pos] = t;
    }
}

__global__ void __launch_bounds__(256) gather_bf16(const float* __restrict__ h2,
                                                   const int* __restrict__ perm,
                                                   unsigned short* __restrict__ Ag) {
    int g = blockIdx.x;
    int row = perm[g];
    unsigned short* dst = Ag + (size_t)g * D_MODEL;
    if (row >= 0) {
        const float* src = h2 + (size_t)row * D_MODEL;
        for (int d = threadIdx.x; d < D_MODEL; d += 256) dst[d] = f2bf(src[d]);
    } else {
        for (int d = threadIdx.x; d < D_MODEL; d += 256) dst[d] = 0;
    }
}

// ---------------- split-bf16 MFMA GEMM (fp32-class accuracy) ---------------
// MODE 0: Cf = A@B            MODE 1: Cf = resid + A@B + bias
template <int MODE>
__global__ void __launch_bounds__(256) sgemm(const unsigned short* __restrict__ Ah_,
                                             const unsigned short* __restrict__ Al_,
                                             const unsigned short* __restrict__ Bh_,
                                             const unsigned short* __restrict__ Bl_,
                                             const float* __restrict__ bias,
                                             const float* __restrict__ resid,
                                             float* __restrict__ Cf,
                                             int N, int K) {
    __shared__ __align__(16) short Ah[128][40];
    __shared__ __align__(16) short Al[128][40];
    __shared__ __align__(16) short Bh[128][40];
    __shared__ __align__(16) short Bl[128][40];

    int row0 = blockIdx.y * 128, n0 = blockIdx.x * 128;
    int tid = threadIdx.x;
    int lane = tid & 63, wid = tid >> 6;
    int wr0 = (wid >> 1) * 64, wc0 = (wid & 1) * 64;
    int lm = lane & 15, q8 = (lane >> 4) * 8;
    int sr = tid >> 2;              // 0..63
    int sc = (tid & 3) * 8;         // 0,8,16,24

    floatx4 acc[4][4];
#pragma unroll
    for (int i = 0; i < 4; i++)
#pragma unroll
        for (int j = 0; j < 4; j++) acc[i][j] = (floatx4){0.f, 0.f, 0.f, 0.f};

    const unsigned short* Ahb = Ah_ + (size_t)row0 * K;
    const unsigned short* Alb = Al_ + (size_t)row0 * K;
    const unsigned short* Bhb = Bh_ + (size_t)n0 * K;
    const unsigned short* Blb = Bl_ + (size_t)n0 * K;

    for (int k0 = 0; k0 < K; k0 += 32) {
        *(uint4*)&Ah[sr][sc]      = *(const uint4*)(Ahb + (size_t)sr * K + k0 + sc);
        *(uint4*)&Ah[sr + 64][sc] = *(const uint4*)(Ahb + (size_t)(sr + 64) * K + k0 + sc);
        *(uint4*)&Al[sr][sc]      = *(const uint4*)(Alb + (size_t)sr * K + k0 + sc);
        *(uint4*)&Al[sr + 64][sc] = *(const uint4*)(Alb + (size_t)(sr + 64) * K + k0 + sc);
        *(uint4*)&Bh[sr][sc]      = *(const uint4*)(Bhb + (size_t)sr * K + k0 + sc);
        *(uint4*)&Bh[sr + 64][sc] = *(const uint4*)(Bhb + (size_t)(sr + 64) * K + k0 + sc);
        *(uint4*)&Bl[sr][sc]      = *(const uint4*)(Blb + (size_t)sr * K + k0 + sc);
        *(uint4*)&Bl[sr + 64][sc] = *(const uint4*)(Blb + (size_t)(sr + 64) * K + k0 + sc);
        __syncthreads();

        short8 ah[4], al[4], bh[4], bl[4];
#pragma unroll
        for (int i = 0; i < 4; i++) {
            ah[i] = *(const short8*)&Ah[wr0 + i * 16 + lm][q8];
            al[i] = *(const short8*)&Al[wr0 + i * 16 + lm][q8];
        }
#pragma unroll
        for (int j = 0; j < 4; j++) {
            bh[j] = *(const short8*)&Bh[wc0 + j * 16 + lm][q8];
            bl[j] = *(const short8*)&Bl[wc0 + j * 16 + lm][q8];
        }
#pragma unroll
        for (int i = 0; i < 4; i++)
#pragma unroll
            for (int j = 0; j < 4; j++) {
                acc[i][j] = __builtin_amdgcn_mfma_f32_16x16x32_bf16(ah[i], bh[j], acc[i][j], 0, 0, 0);
                acc[i][j] = __builtin_amdgcn_mfma_f32_16x16x32_bf16(ah[i], bl[j], acc[i][j], 0, 0, 0);
                acc[i][j] = __builtin_amdgcn_mfma_f32_16x16x32_bf16(al[i], bh[j], acc[i][j], 0, 0, 0);
            }
        __syncthreads();
    }

    int q4 = (lane >> 4) * 4;
#pragma unroll
    for (int i = 0; i < 4; i++) {
#pragma unroll
        for (int j = 0; j < 4; j++) {
            int c = n0 + wc0 + j * 16 + lm;
#pragma unroll
            for (int reg = 0; reg < 4; reg++) {
                int rloc = wr0 + i * 16 + q4 + reg;
                size_t idx = (size_t)(row0 + rloc) * N + c;
                float v = acc[i][j][reg];
                if constexpr (MODE == 0) Cf[idx] = v;
                else                     Cf[idx] = resid[idx] + v + bias[c];
            }
        }
    }
}

// ---------------- bf16 MFMA GEMM (MoE; R4-verified) ------------------------
template <int MODE>
__global__ void __launch_bounds__(256) mgemm(const unsigned short* __restrict__ A,
                                             const unsigned short* __restrict__ Bt,
                                             const float* __restrict__ bias,
                                             const float* __restrict__ resid,
                                             float* __restrict__ Cf,
                                             unsigned short* __restrict__ Cb,
                                             int N, int K,
                                             const int* __restrict__ perm,
                                             const int* __restrict__ tile_e,
                                             const int* __restrict__ tile_row0,
                                             const int* __restrict__ ntiles) {
    __shared__ __align__(16) short As[128][40];
    __shared__ __align__(16) short Bs[128][40];

    if ((int)blockIdx.y >= ntiles[0]) return;
    int e = tile_e[blockIdx.y];
    int row0 = tile_row0[blockIdx.y];
    Bt += (size_t)e * N * K;
    bias += (size_t)e * N;
    int n0 = blockIdx.x * 128;

    int tid = threadIdx.x;
    int lane = tid & 63, wid = tid >> 6;
    int wr0 = (wid >> 1) * 64, wc0 = (wid & 1) * 64;
    int lm = lane & 15, q8 = (lane >> 4) * 8;
    int sr = tid >> 2;
    int sc = (tid & 3) * 8;

    floatx4 acc[4][4];
#pragma unroll
    for (int i = 0; i < 4; i++)
#pragma unroll
        for (int j = 0; j < 4; j++) acc[i][j] = (floatx4){0.f, 0.f, 0.f, 0.f};

    const unsigned short* Abase = A + (size_t)row0 * K;
    const unsigned short* Bbase = Bt + (size_t)n0 * K;

    for (int k0 = 0; k0 < K; k0 += 32) {
        *(uint4*)&As[sr][sc]      = *(const uint4*)(Abase + (size_t)sr * K + k0 + sc);
        *(uint4*)&As[sr + 64][sc] = *(const uint4*)(Abase + (size_t)(sr + 64) * K + k0 + sc);
        *(uint4*)&Bs[sr][sc]      = *(const uint4*)(Bbase + (size_t)sr * K + k0 + sc);
        *(uint4*)&Bs[sr + 64][sc] = *(const uint4*)(Bbase + (size_t)(sr + 64) * K + k0 + sc);
        __syncthreads();

        short8 af[4], bfr[4];
#pragma unroll
        for (int i = 0; i < 4; i++)
            af[i] = *(const short8*)&As[wr0 + i * 16 + lm][q8];
#pragma unroll
        for (int j = 0; j < 4; j++)
            bfr[j] = *(const short8*)&Bs[wc0 + j * 16 + lm][q8];
#pragma unroll
        for (int i = 0; i < 4; i++)
#pragma unroll
            for (int j = 0; j < 4; j++)
                acc[i][j] = __builtin_amdgcn_mfma_f32_16x16x32_bf16(af[i], bfr[j], acc[i][j], 0, 0, 0);
        __syncthreads();
    }

    int q4 = (lane >> 4) * 4;
#pragma unroll
    for (int i = 0; i < 4; i++) {
#pragma unroll
        for (int j = 0; j < 4; j++) {
            int c = n0 + wc0 + j * 16 + lm;
#pragma unroll
            for (int reg = 0; reg < 4; reg++) {
                int rloc = wr0 + i * 16 + q4 + reg;
                float v = acc[i][j][reg];
                if constexpr (MODE == 2) {
                    Cb[(size_t)(row0 + rloc) * N + c] = f2bf(gelu_exact(v + bias[c]));
                } else {
                    int t = perm[row0 + rloc];
                    if (t >= 0) {
                        size_t idx = (size_t)t * N + c;
                        Cf[idx] = resid[idx] + gelu_exact(v + bias[c]);
                    }
                }
            }
        }
    }
}

extern "C" void kernel_launch(void* const* d_in, const int* in_sizes, int n_in,
                              void* d_out, int out_size, void* d_ws, size_t ws_size,
                              hipStream_t stream) {
    const float* x      = (const float*)d_in[0];
    const float* ln1_g  = (const float*)d_in[2];
    const float* ln1_b  = (const float*)d_in[3];
    const float* qkv_w  = (const float*)d_in[4];
    const float* proj_w = (const float*)d_in[5];
    const float* proj_b = (const float*)d_in[6];
    const float* ln2_g  = (const float*)d_in[7];
    const float* ln2_b  = (const float*)d_in[8];
    const float* sw     = (const float*)d_in[9];
    const float* sb     = (const float*)d_in[10];
    const float* w1     = (const float*)d_in[11];
    const float* b1     = (const float*)d_in[12];
    const float* w2     = (const float*)d_in[13];
    const float* b2     = (const float*)d_in[14];
    float* out = (float*)d_out;

    // ---- workspace layout ----
    char* p = (char*)d_ws;
    float*          qkv = (float*)p;
    float*          h   = (float*)p;
    unsigned short* y1  = (unsigned short*)p;
    p += (size_t)T_TOK * 2304 * 4;
    unsigned short* h_hi = (unsigned short*)p; p += (size_t)T_TOK * D_MODEL * 2;
    unsigned short* h_lo = (unsigned short*)p; p += (size_t)T_TOK * D_MODEL * 2;
    unsigned short* o_hi = h_hi;
    unsigned short* o_lo = h_lo;
    float* x1 = (float*)p; p += (size_t)T_TOK * D_MODEL * 4;
    unsigned short* Ag     = (unsigned short*)p;
    unsigned short* qwt_hi = (unsigned short*)p;
    unsigned short* qwt_lo = qwt_hi + (size_t)2304 * 768;
    p += (size_t)MPAD_MAX * D_MODEL * 2;
    unsigned short* pwt_hi = (unsigned short*)p; p += (size_t)768 * 768 * 2;
    unsigned short* pwt_lo = (unsigned short*)p; p += (size_t)768 * 768 * 2;
    unsigned short* w1t = (unsigned short*)p; p += (size_t)E_EXP * 3072 * 768 * 2;
    unsigned short* w2t = (unsigned short*)p; p += (size_t)E_EXP * 768 * 3072 * 2;
    int* routes    = (int*)p;
    int* perm      = routes + T_TOK;
    int* counts    = perm + MPAD_MAX;
    int* cursor    = counts + 8;
    int* pad_base  = cursor + 8;
    int* tile_e    = pad_base + 8;
    int* tile_row0 = tile_e + MAX_TILES;
    int* ntiles    = tile_row0 + MAX_TILES;

    // ---- weight preprocessing ----
    transpose_split<<<dim3(2304 / 32, 768 / 32), 256, 0, stream>>>(qkv_w, qwt_hi, qwt_lo, 768, 2304);
    transpose_split<<<dim3(768 / 32, 768 / 32), 256, 0, stream>>>(proj_w, pwt_hi, pwt_lo, 768, 768);
    transpose_bf16<<<dim3(3072 / 32, 768 / 32, 8), 256, 0, stream>>>(w1, w1t, 768, 3072);
    transpose_bf16<<<dim3(768 / 32, 3072 / 32, 8), 256, 0, stream>>>(w2, w2t, 3072, 768);

    // 1. LN1 -> split bf16 (h_hi, h_lo)
    ln_split<<<T_TOK, 256, 0, stream>>>(x, ln1_g, ln1_b, h_hi, h_lo);
    // 2. QKV (split-bf16 MFMA): qkv = h @ qkv_w   [4096 x 2304, K=768]
    sgemm<0><<<dim3(2304 / 128, T_TOK / 128), 256, 0, stream>>>(
        h_hi, h_lo, qwt_hi, qwt_lo, nullptr, nullptr, qkv, 2304, 768);
    // 3. Attention (split-bf16 MFMA flash) -> split bf16 o
    attn_mfma<<<dim3(S_SEQ / 64, H_HEADS, B_BATCH), 256, 0, stream>>>(qkv, o_hi, o_lo);
    // 4. Proj + residual (split-bf16 MFMA): x1 = x + o@proj_w + proj_b
    sgemm<1><<<dim3(768 / 128, T_TOK / 128), 256, 0, stream>>>(
        o_hi, o_lo, pwt_hi, pwt_lo, proj_b, x, x1, 768, 768);
    // 5. LN2 -> fp32 h (router path: exact fp32)
    ln_f32<<<T_TOK, 256, 0, stream>>>(x1, ln2_g, ln2_b, h);
    // 6-9. Routing (fp32, unchanged)
    init_kernel<<<(MPAD_MAX + 255) / 256, 256, 0, stream>>>(counts, cursor, perm);
    router_kernel<<<T_TOK, 64, 0, stream>>>(h, sw, sb, routes, counts);
    moe_plan<<<1, 1, 0, stream>>>(counts, pad_base, tile_e, tile_row0, ntiles);
    scatter_kernel<<<T_TOK / 256, 256, 0, stream>>>(routes, pad_base, cursor, perm);
    // 10. Gather routed rows -> packed bf16 A
    gather_bf16<<<MPAD_MAX, 256, 0, stream>>>(h, perm, Ag);
    // 11. MoE up (bf16 MFMA): y1 = bf16(gelu(Ag @ w1t[e] + b1[e]))
    mgemm<2><<<dim3(FF_DIM / 128, MAX_TILES), 256, 0, stream>>>(
        Ag, w1t, b1, nullptr, nullptr, y1, FF_DIM, 768,
        perm, tile_e, tile_row0, ntiles);
    // 12. MoE down + residual scatter (bf16 MFMA)
    mgemm<3><<<dim3(D_MODEL / 128, MAX_TILES), 256, 0, stream>>>(
        y1, w2t, b2, x1, out, nullptr, D_MODEL, 3072,
        perm, tile_e, tile_row0, ntiles);
}